// Round 1
// baseline (470.808 us; speedup 1.0000x reference)
//
#include <hip/hip_runtime.h>
#include <hip/hip_bf16.h>

typedef unsigned short u16;
typedef unsigned int u32;
typedef __bf16 bf16x8 __attribute__((ext_vector_type(8)));
typedef u16 u16x8 __attribute__((ext_vector_type(8)));
typedef float f32x4 __attribute__((ext_vector_type(4)));
typedef float f32x16 __attribute__((ext_vector_type(16)));

#define MM   4096      // B*L
#define CC   4000      // char vocab (K of gemm1)
#define DD   512       // d_vec
#define VV   10000     // emb rows
#define VPAD 10048     // 157*64, zero-padded tail
#define NT   157       // V tiles of 64
#define VSPLIT 8
#define TPC  20        // tiles per V-chunk (last chunk gets 17)

// ws layout (bytes)
#define WS_Q    0u          // Qb   bf16 [4096][512]   = 4,194,304
#define WS_EB   4194304u    // Eb   bf16 [10048][512]  = 10,289,152
#define WS_ET   14483456u   // ET   bf16 [512][10048]  = 10,289,152
#define WS_OACC 24772608u   // Oacc f32  [4096][512]   = 8,388,608
#define WS_LACC 33161216u   // Lacc f32  [4096]        = 16,384

__device__ __forceinline__ u16 f2bf(float f) {
  u32 u = __builtin_bit_cast(u32, f);
  return (u16)((u + 0x7FFFu + ((u >> 16) & 1u)) >> 16);  // RNE
}
__device__ __forceinline__ float bf2f(u16 h) {
  u32 u = (u32)h << 16;
  return __builtin_bit_cast(float, u);
}

// ---------------------------------------------------------------- k0: E prep
// Eb row-major bf16, ET transposed bf16, zero pad v in [VV, VPAD).
// Also zeroes Oacc++Lacc (contiguous 2,101,248 floats).
__global__ __launch_bounds__(256) void k_eprep(const float* __restrict__ E,
                                               u16* __restrict__ Eb,
                                               u16* __restrict__ ETb,
                                               float* __restrict__ Zacc) {
  int tid = threadIdx.x;
  {
    int fid = (blockIdx.x * (int)gridDim.y + blockIdx.y) * 256 + tid;
    if (fid < (MM * DD + MM) / 4) {
      f32x4 z = {0.f, 0.f, 0.f, 0.f};
      *(f32x4*)(Zacc + (size_t)fid * 4) = z;
    }
  }
  int v = blockIdx.x * 64 + (tid & 63);       // lane-contiguous v -> ET stores coalesce
  int dblk = blockIdx.y * 4 + (tid >> 6);
  int d0 = dblk * 8;
  u16 h[8];
  if (v < VV) {
    const float* src = E + (size_t)v * DD + d0;
    float4 a = *(const float4*)src;
    float4 b = *(const float4*)(src + 4);
    h[0] = f2bf(a.x); h[1] = f2bf(a.y); h[2] = f2bf(a.z); h[3] = f2bf(a.w);
    h[4] = f2bf(b.x); h[5] = f2bf(b.y); h[6] = f2bf(b.z); h[7] = f2bf(b.w);
  } else {
    #pragma unroll
    for (int i = 0; i < 8; ++i) h[i] = 0;
  }
  u16x8 pack;
  #pragma unroll
  for (int i = 0; i < 8; ++i) pack[i] = h[i];
  *(u16x8*)(Eb + (size_t)v * DD + d0) = pack;
  #pragma unroll
  for (int i = 0; i < 8; ++i) ETb[(size_t)(d0 + i) * VPAD + v] = h[i];
}

// ---------------------------------------------------- k1: q = tanh(x @ W^T)
// 64x64 tile, BK=64, 16x16x32 bf16 MFMA, inline f32->bf16, XOR-8 swizzled LDS.
// LDS elem addr (u16 units): row*64 + (((k>>3) ^ (row&7))<<3) + (k&7)
__global__ __launch_bounds__(256) void k_gemm1(const float* __restrict__ X,
                                               const float* __restrict__ W,
                                               u16* __restrict__ Qb) {
  __shared__ u16 xs[64 * 64];
  __shared__ u16 wst[64 * 64];
  int tid = threadIdx.x;
  int m0 = blockIdx.x * 64;
  int n0 = blockIdx.y * 64;
  int srow = tid >> 2;         // staging row 0..63
  int sseg = tid & 3;          // 16-col segment
  int r7 = srow & 7;
  const float* xsrc = X + (size_t)(m0 + srow) * CC + sseg * 16;
  const float* wsrc = W + (size_t)(n0 + srow) * CC + sseg * 16;
  int lane = tid & 63;
  int wv = tid >> 6;
  int l15 = lane & 15, quad = lane >> 4;
  f32x4 acc[4] = {};

  for (int kt = 0; kt < 63; ++kt) {          // 63*64 = 4032 >= 4000
    int cbase = kt * 64 + sseg * 16;
    float xv[16], wf[16];
    if (cbase + 16 <= CC) {                  // 4000 % 16 == 0: all-or-nothing
      #pragma unroll
      for (int j = 0; j < 4; ++j) {
        float4 tx = *(const float4*)(xsrc + kt * 64 + j * 4);
        float4 tw = *(const float4*)(wsrc + kt * 64 + j * 4);
        xv[4*j+0] = tx.x; xv[4*j+1] = tx.y; xv[4*j+2] = tx.z; xv[4*j+3] = tx.w;
        wf[4*j+0] = tw.x; wf[4*j+1] = tw.y; wf[4*j+2] = tw.z; wf[4*j+3] = tw.w;
      }
    } else {
      #pragma unroll
      for (int j = 0; j < 16; ++j) { xv[j] = 0.f; wf[j] = 0.f; }
    }
    __syncthreads();
    #pragma unroll
    for (int j = 0; j < 2; ++j) {
      int g = (sseg * 2 + j) ^ r7;
      u16x8 px, pw;
      #pragma unroll
      for (int e = 0; e < 8; ++e) { px[e] = f2bf(xv[8*j+e]); pw[e] = f2bf(wf[8*j+e]); }
      *(u16x8*)&xs[srow * 64 + (g << 3)] = px;
      *(u16x8*)&wst[srow * 64 + (g << 3)] = pw;
    }
    __syncthreads();
    #pragma unroll
    for (int kk = 0; kk < 2; ++kk) {
      int arow = 16 * wv + l15;
      int ga = (kk * 4 + quad) ^ (arow & 7);
      bf16x8 a = *(const bf16x8*)&xs[arow * 64 + (ga << 3)];
      #pragma unroll
      for (int nb = 0; nb < 4; ++nb) {
        int brow = 16 * nb + l15;
        int gb = (kk * 4 + quad) ^ (brow & 7);
        bf16x8 b = *(const bf16x8*)&wst[brow * 64 + (gb << 3)];
        acc[nb] = __builtin_amdgcn_mfma_f32_16x16x32_bf16(a, b, acc[nb], 0, 0, 0);
      }
    }
  }
  // C/D 16x16: row = 4*quad + reg, col = lane&15  (m89-verified mapping)
  #pragma unroll
  for (int nb = 0; nb < 4; ++nb) {
    int d = n0 + 16 * nb + l15;
    #pragma unroll
    for (int r = 0; r < 4; ++r) {
      int m = m0 + 16 * wv + 4 * quad + r;
      Qb[(size_t)m * DD + d] = f2bf(tanhf(acc[nb][r]));
    }
  }
}

// ------------------------------------------- k2: fused softmax-attention
// grid = 64 rowgroups x 8 V-chunks. Mt=64, Vt=64, 32x32x16 bf16 MFMA.
// No max-subtraction needed: |logit| <= 51.2 guaranteed -> exp(s) safe in fp32.
// Partial O (fp32) and l accumulate into global via atomicAdd.
__global__ __launch_bounds__(256, 2) void k_attn(const u16* __restrict__ Qb,
                                                 const u16* __restrict__ Eb,
                                                 const u16* __restrict__ ETb,
                                                 float* __restrict__ Oacc,
                                                 float* __restrict__ Lacc) {
  __shared__ u16 qs[64 * 512];   // 64 KB, swizzled (k-groups of 8 XOR row&7)
  __shared__ u16 ps[64 * 64];    // 8 KB P tile, same swizzle
  __shared__ float ls[64];

  int tid = threadIdx.x;
  int bid = blockIdx.x;
  int rg = bid >> 3;
  int chunk = bid & 7;
  int m0 = rg * 64;
  int t0 = chunk * TPC;
  int t1 = t0 + TPC; if (t1 > NT) t1 = NT;

  { // stage q tile
    int row = tid >> 2, seg = tid & 3;
    int rr7 = row & 7;
    const u16* src = Qb + (size_t)(m0 + row) * DD + seg * 128;
    #pragma unroll
    for (int i = 0; i < 16; ++i) {
      int g = (seg * 16 + i) ^ rr7;
      *(u16x8*)&qs[row * 512 + (g << 3)] = *(const u16x8*)(src + i * 8);
    }
  }
  if (tid < 64) ls[tid] = 0.f;
  __syncthreads();

  int lane = tid & 63;
  int wv = tid >> 6;
  int l31 = lane & 31, h = lane >> 5;
  int mfrag = wv >> 1;     // S phase: which 32 rows
  int vfrag = wv & 1;      // S phase: which 32 cols of the V tile

  f32x16 o[2][4] = {};     // [mfrag][i], d-frag = 4*wv + i  -> 128 acc VGPRs

  for (int t = t0; t < t1; ++t) {
    int vbase = t * 64;
    // ---- S = q @ E^T (one 32x32 frag per wave, K=512)
    f32x16 s = {};
    {
      int arow = 32 * mfrag + l31;
      int ar7 = arow & 7;
      int abase = arow * 512;
      const u16* ebrow = Eb + (size_t)(vbase + 32 * vfrag + l31) * DD + 8 * h;
      #pragma unroll 4
      for (int kk = 0; kk < 32; ++kk) {
        int g = (2 * kk + h) ^ ar7;
        bf16x8 a = *(const bf16x8*)&qs[abase + (g << 3)];
        bf16x8 b = *(const bf16x8*)(ebrow + kk * 16);
        s = __builtin_amdgcn_mfma_f32_32x32x16_bf16(a, b, s, 0, 0, 0);
      }
    }
    // ---- P = exp(S), mask padded v, write to LDS (bf16)
    {
      int vg = vbase + 32 * vfrag + l31;
      bool ok = vg < VV;
      int cv = 32 * vfrag + l31;
      int cg = cv >> 3, ce = cv & 7;
      #pragma unroll
      for (int r = 0; r < 16; ++r) {
        // C/D 32x32: row = (r&3)+8*(r>>2)+4*h, col = lane&31 (m74/m101-verified)
        int row = 32 * mfrag + (r & 3) + 8 * (r >> 2) + 4 * h;
        float p = ok ? __expf(s[r]) : 0.f;
        ps[row * 64 + ((cg ^ (row & 7)) << 3) + ce] = f2bf(p);
      }
    }
    __syncthreads();
    // ---- l += rowsum(P)  (from the same bf16 P the PV mfma consumes)
    {
      int row = tid >> 2, q4 = tid & 3;
      int rr7 = row & 7;
      float sum = 0.f;
      #pragma unroll
      for (int j = 0; j < 2; ++j) {
        int g = (q4 * 2 + j) ^ rr7;
        const u16* p8 = &ps[row * 64 + (g << 3)];
        #pragma unroll
        for (int e = 0; e < 8; ++e) sum += bf2f(p8[e]);
      }
      atomicAdd(&ls[row], sum);
    }
    // ---- O += P @ E  (wave owns d-frag 4*wv+i for BOTH row halves; ET read once/WG)
    {
      #pragma unroll
      for (int ks = 0; ks < 4; ++ks) {
        int g0 = (2 * ks + h) ^ (l31 & 7);
        bf16x8 a0 = *(const bf16x8*)&ps[l31 * 64 + (g0 << 3)];
        int r1 = 32 + l31;
        int g1 = (2 * ks + h) ^ (r1 & 7);
        bf16x8 a1 = *(const bf16x8*)&ps[r1 * 64 + (g1 << 3)];
        #pragma unroll
        for (int i = 0; i < 4; ++i) {
          int d = 32 * (4 * wv + i) + l31;
          bf16x8 b = *(const bf16x8*)(ETb + (size_t)d * VPAD + vbase + ks * 16 + 8 * h);
          o[0][i] = __builtin_amdgcn_mfma_f32_32x32x16_bf16(a0, b, o[0][i], 0, 0, 0);
          o[1][i] = __builtin_amdgcn_mfma_f32_32x32x16_bf16(a1, b, o[1][i], 0, 0, 0);
        }
      }
    }
    __syncthreads();
  }

  if (tid < 64) atomicAdd(&Lacc[m0 + tid], ls[tid]);
  #pragma unroll
  for (int mf = 0; mf < 2; ++mf)
    #pragma unroll
    for (int i = 0; i < 4; ++i) {
      int d = 32 * (4 * wv + i) + l31;
      #pragma unroll
      for (int r = 0; r < 16; ++r) {
        int m = m0 + 32 * mf + (r & 3) + 8 * (r >> 2) + 4 * h;
        atomicAdd(&Oacc[(size_t)m * DD + d], o[mf][i][r]);
      }
    }
}

// ------------------------------------------- k3: out = O/l + q
__global__ __launch_bounds__(256) void k_combine(const float* __restrict__ Oacc,
                                                 const float* __restrict__ Lacc,
                                                 const u16* __restrict__ Qb,
                                                 float* __restrict__ out) {
  int idx = blockIdx.x * 256 + threadIdx.x;  // one float4 per thread
  int m = idx >> 7;
  int d4 = (idx & 127) * 4;
  float inv = 1.f / Lacc[m];
  f32x4 ov = *(const f32x4*)(Oacc + (size_t)m * DD + d4);
  const u16* qp = Qb + (size_t)m * DD + d4;
  f32x4 r;
  #pragma unroll
  for (int i = 0; i < 4; ++i) r[i] = ov[i] * inv + bf2f(qp[i]);
  *(f32x4*)(out + (size_t)m * DD + d4) = r;
}

extern "C" void kernel_launch(void* const* d_in, const int* in_sizes, int n_in,
                              void* d_out, int out_size, void* d_ws, size_t ws_size,
                              hipStream_t stream) {
  const float* x  = (const float*)d_in[0];
  const float* Wp = (const float*)d_in[1];
  const float* E  = (const float*)d_in[2];
  float* out = (float*)d_out;
  char* ws = (char*)d_ws;
  u16*   Qb   = (u16*)(ws + WS_Q);
  u16*   Eb   = (u16*)(ws + WS_EB);
  u16*   ETb  = (u16*)(ws + WS_ET);
  float* Oacc = (float*)(ws + WS_OACC);
  float* Lacc = (float*)(ws + WS_LACC);

  k_eprep<<<dim3(NT, 16), 256, 0, stream>>>(E, Eb, ETb, Oacc);
  k_gemm1<<<dim3(MM / 64, DD / 64), 256, 0, stream>>>(x, Wp, Qb);
  k_attn<<<dim3(64 * VSPLIT), 256, 0, stream>>>(Qb, Eb, ETb, Oacc, Lacc);
  k_combine<<<dim3(MM * DD / 4 / 256), 256, 0, stream>>>(Oacc, Lacc, Qb, out);
}

// Round 2
// 461.126 us; speedup vs baseline: 1.0210x; 1.0210x over previous
//
#include <hip/hip_runtime.h>
#include <hip/hip_bf16.h>

typedef unsigned short u16;
typedef unsigned int u32;
typedef __bf16 bf16x8 __attribute__((ext_vector_type(8)));
typedef u16 u16x8 __attribute__((ext_vector_type(8)));
typedef float f32x4 __attribute__((ext_vector_type(4)));

#define MM   4096      // B*L
#define CC   4000      // char vocab (K of gemm1)
#define DD   512       // d_vec
#define VV   10000     // emb rows
#define VPAD 10240     // 80*128, zero-padded tail

// ws layout (bytes)
#define WS_Q    0u          // Qb   bf16 [4096][512]    = 4,194,304
#define WS_EB   4194304u    // Eb   bf16 [10240][512]   = 10,485,760
#define WS_ET   14680064u   // ET   bf16 [512][10240]   = 10,485,760
#define WS_LACC 25165824u   // Lacc f32  [4096]         = 16,384
#define WS_P    25182208u   // Pc   bf16 [4096][W]      (W chosen from ws_size)

__device__ __forceinline__ u16 f2bf(float f) {
  u32 u = __builtin_bit_cast(u32, f);
  return (u16)((u + 0x7FFFu + ((u >> 16) & 1u)) >> 16);  // RNE
}
__device__ __forceinline__ float bf2f(u16 h) {
  u32 u = (u32)h << 16;
  return __builtin_bit_cast(float, u);
}

// async global->LDS, 16B per lane; LDS dest is wave-uniform base + lane*16
#define GLDS(gp, lp) __builtin_amdgcn_global_load_lds( \
    (const __attribute__((address_space(1))) void*)(gp), \
    (__attribute__((address_space(3))) void*)(lp), 16, 0, 0)

// ---------------------------------------------------------------- k0: E prep
// Per block: 64v x 64d tile. Coalesced read of E, coalesced writes of Eb and
// (via LDS transpose) ET. Zero pad v in [VV, VPAD). Also zeroes d_out + Lacc.
__global__ __launch_bounds__(256) void k_eprep(const float* __restrict__ E,
                                               u16* __restrict__ Eb,
                                               u16* __restrict__ ETb,
                                               float* __restrict__ Out,
                                               float* __restrict__ Lacc) {
  __shared__ u16 st[64 * 65];
  int tid = threadIdx.x;
  // zero d_out (4096*512 f32) and Lacc (4096 f32), in f32x4 groups
  {
    int bid = blockIdx.x * 8 + blockIdx.y;
    f32x4 z = {0.f, 0.f, 0.f, 0.f};
    #pragma unroll
    for (int rep = 0; rep < 2; ++rep) {
      int id = bid * 256 + tid + rep * 327680;
      if (id < 524288)      *(f32x4*)(Out + (size_t)id * 4) = z;
      else if (id < 525312) *(f32x4*)(Lacc + (size_t)(id - 524288) * 4) = z;
    }
  }
  int v0 = blockIdx.x * 64, d0 = blockIdx.y * 64;
  int r = tid >> 2, seg = tid & 3;        // row within tile, 16-col segment
  u16 h[16];
  int v = v0 + r;
  if (v < VV) {
    const float* src = E + (size_t)v * DD + d0 + seg * 16;
    #pragma unroll
    for (int j = 0; j < 4; ++j) {
      float4 t = *(const float4*)(src + j * 4);
      h[4*j+0] = f2bf(t.x); h[4*j+1] = f2bf(t.y); h[4*j+2] = f2bf(t.z); h[4*j+3] = f2bf(t.w);
    }
  } else {
    #pragma unroll
    for (int j = 0; j < 16; ++j) h[j] = 0;
  }
  { // Eb row-major store (coalesced)
    u16x8 p0, p1;
    #pragma unroll
    for (int j = 0; j < 8; ++j) { p0[j] = h[j]; p1[j] = h[8+j]; }
    u16* dst = Eb + (size_t)v * DD + d0 + seg * 16;
    *(u16x8*)dst = p0; *(u16x8*)(dst + 8) = p1;
  }
  #pragma unroll
  for (int j = 0; j < 16; ++j) st[r * 65 + seg * 16 + j] = h[j];
  __syncthreads();
  { // ET store: thread owns row d0+r, v-segment seg*16..+15 (coalesced)
    u16 g[16];
    #pragma unroll
    for (int j = 0; j < 16; ++j) g[j] = st[(seg * 16 + j) * 65 + r];
    u16x8 p0, p1;
    #pragma unroll
    for (int j = 0; j < 8; ++j) { p0[j] = g[j]; p1[j] = g[8+j]; }
    u16* dst = ETb + (size_t)(d0 + r) * VPAD + v0 + seg * 16;
    *(u16x8*)dst = p0; *(u16x8*)(dst + 8) = p1;
  }
}

// ---------------------------------------------------- k1: q = tanh(x @ W^T)
// (kept from round 1 — known good; will revisit after profiling its share)
__global__ __launch_bounds__(256) void k_gemm1(const float* __restrict__ X,
                                               const float* __restrict__ W,
                                               u16* __restrict__ Qb) {
  __shared__ u16 xs[64 * 64];
  __shared__ u16 wst[64 * 64];
  int tid = threadIdx.x;
  int m0 = blockIdx.x * 64;
  int n0 = blockIdx.y * 64;
  int srow = tid >> 2;
  int sseg = tid & 3;
  int r7 = srow & 7;
  const float* xsrc = X + (size_t)(m0 + srow) * CC + sseg * 16;
  const float* wsrc = W + (size_t)(n0 + srow) * CC + sseg * 16;
  int lane = tid & 63;
  int wv = tid >> 6;
  int l15 = lane & 15, quad = lane >> 4;
  f32x4 acc[4] = {};

  for (int kt = 0; kt < 63; ++kt) {
    int cbase = kt * 64 + sseg * 16;
    float xv[16], wf[16];
    if (cbase + 16 <= CC) {
      #pragma unroll
      for (int j = 0; j < 4; ++j) {
        float4 tx = *(const float4*)(xsrc + kt * 64 + j * 4);
        float4 tw = *(const float4*)(wsrc + kt * 64 + j * 4);
        xv[4*j+0] = tx.x; xv[4*j+1] = tx.y; xv[4*j+2] = tx.z; xv[4*j+3] = tx.w;
        wf[4*j+0] = tw.x; wf[4*j+1] = tw.y; wf[4*j+2] = tw.z; wf[4*j+3] = tw.w;
      }
    } else {
      #pragma unroll
      for (int j = 0; j < 16; ++j) { xv[j] = 0.f; wf[j] = 0.f; }
    }
    __syncthreads();
    #pragma unroll
    for (int j = 0; j < 2; ++j) {
      int g = (sseg * 2 + j) ^ r7;
      u16x8 px, pw;
      #pragma unroll
      for (int e = 0; e < 8; ++e) { px[e] = f2bf(xv[8*j+e]); pw[e] = f2bf(wf[8*j+e]); }
      *(u16x8*)&xs[srow * 64 + (g << 3)] = px;
      *(u16x8*)&wst[srow * 64 + (g << 3)] = pw;
    }
    __syncthreads();
    #pragma unroll
    for (int kk = 0; kk < 2; ++kk) {
      int arow = 16 * wv + l15;
      int ga = (kk * 4 + quad) ^ (arow & 7);
      bf16x8 a = *(const bf16x8*)&xs[arow * 64 + (ga << 3)];
      #pragma unroll
      for (int nb = 0; nb < 4; ++nb) {
        int brow = 16 * nb + l15;
        int gb = (kk * 4 + quad) ^ (brow & 7);
        bf16x8 b = *(const bf16x8*)&wst[brow * 64 + (gb << 3)];
        acc[nb] = __builtin_amdgcn_mfma_f32_16x16x32_bf16(a, b, acc[nb], 0, 0, 0);
      }
    }
  }
  #pragma unroll
  for (int nb = 0; nb < 4; ++nb) {
    int d = n0 + 16 * nb + l15;
    #pragma unroll
    for (int r = 0; r < 4; ++r) {
      int m = m0 + 16 * wv + 4 * quad + r;
      Qb[(size_t)m * DD + d] = f2bf(tanhf(acc[nb][r]));
    }
  }
}

// -------------------------------------- k2: P = exp(q @ E^T), l += rowsum(P)
// m97-skeleton: 128x128 tile, BK=64, global_load_lds(16B) staging with
// source-side XOR swizzle so frag ds_read_b128 are 2-way (free) conflicts.
// No max-subtraction: |logit| <= 51.2 guaranteed (tanh-bounded q, |E|<=0.1).
__global__ __launch_bounds__(256) void k_s(const u16* __restrict__ Qb,
                                           const u16* __restrict__ Eb,
                                           u16* __restrict__ Pg,
                                           float* __restrict__ Lacc,
                                           int cbase, int W) {
  __shared__ u16 As[128 * 64];   // 16 KB  [row][k], k-chunks-of-8 XOR row&7
  __shared__ u16 Bs[128 * 64];   // 16 KB
  int tid = threadIdx.x;
  int m0 = blockIdx.x * 128;
  int n0 = blockIdx.y * 128;     // within chunk
  int w = tid >> 6, l = tid & 63;
  int l15 = l & 15, quad = l >> 4;
  int mhalf = w >> 1, nhalf = w & 1;
  int lr = l >> 3, lg = l & 7;   // staging: lane's (row-in-octet, slot)
  f32x4 acc[4][4] = {};

  for (int kt = 0; kt < 8; ++kt) {
    #pragma unroll
    for (int i = 0; i < 4; ++i) {
      int wc = i * 4 + w;
      int row = wc * 8 + lr;
      int g = lg ^ (row & 7);
      GLDS(Qb + (size_t)(m0 + row) * DD + kt * 64 + g * 8, As + wc * 512);
      GLDS(Eb + (size_t)(cbase + n0 + row) * DD + kt * 64 + g * 8, Bs + wc * 512);
    }
    __syncthreads();
    #pragma unroll
    for (int kk = 0; kk < 2; ++kk) {
      bf16x8 a[4], b[4];
      #pragma unroll
      for (int mi = 0; mi < 4; ++mi) {
        int arow = mhalf * 64 + mi * 16 + l15;
        int slot = (kk * 4 + quad) ^ (arow & 7);
        a[mi] = *(const bf16x8*)&As[arow * 64 + slot * 8];
      }
      #pragma unroll
      for (int ni = 0; ni < 4; ++ni) {
        int brow = nhalf * 64 + ni * 16 + l15;
        int slot = (kk * 4 + quad) ^ (brow & 7);
        b[ni] = *(const bf16x8*)&Bs[brow * 64 + slot * 8];
      }
      #pragma unroll
      for (int mi = 0; mi < 4; ++mi)
        #pragma unroll
        for (int ni = 0; ni < 4; ++ni)
          acc[mi][ni] = __builtin_amdgcn_mfma_f32_16x16x32_bf16(a[mi], b[ni], acc[mi][ni], 0, 0, 0);
    }
    __syncthreads();
  }

  // epilogue: exp + mask + store P (bf16) + per-row sums -> Lacc
  float rs[4][4] = {};
  #pragma unroll
  for (int mi = 0; mi < 4; ++mi) {
    #pragma unroll
    for (int ni = 0; ni < 4; ++ni) {
      int ncol = n0 + nhalf * 64 + ni * 16 + l15;
      bool ok = (cbase + ncol) < VV;
      #pragma unroll
      for (int r = 0; r < 4; ++r) {
        float p = ok ? __expf(acc[mi][ni][r]) : 0.f;
        rs[mi][r] += p;
        int m = m0 + mhalf * 64 + mi * 16 + quad * 4 + r;
        Pg[(size_t)m * W + ncol] = f2bf(p);
      }
    }
  }
  #pragma unroll
  for (int mi = 0; mi < 4; ++mi)
    #pragma unroll
    for (int r = 0; r < 4; ++r) {
      float v = rs[mi][r];
      v += __shfl_xor(v, 1, 16);
      v += __shfl_xor(v, 2, 16);
      v += __shfl_xor(v, 4, 16);
      v += __shfl_xor(v, 8, 16);
      if (l15 == 0)
        atomicAdd(&Lacc[m0 + mhalf * 64 + mi * 16 + quad * 4 + r], v);
    }
}

// -------------------------------------- k3: Out += P @ E   (RMW f32, no atomics)
// 128x64 tile, K = W (chunk width). B read from ET [512][VPAD].
__global__ __launch_bounds__(256) void k_pv(const u16* __restrict__ Pg,
                                            const u16* __restrict__ ETb,
                                            float* __restrict__ Out,
                                            int cbase, int W) {
  __shared__ u16 As[128 * 64];   // 16 KB
  __shared__ u16 Bs[64 * 64];    // 8 KB
  int tid = threadIdx.x;
  int m0 = blockIdx.x * 128;
  int n0 = blockIdx.y * 64;      // d offset
  int w = tid >> 6, l = tid & 63;
  int l15 = l & 15, quad = l >> 4;
  int lr = l >> 3, lg = l & 7;
  int iters = W >> 6;
  f32x4 acc[2][4] = {};

  for (int kt = 0; kt < iters; ++kt) {
    #pragma unroll
    for (int i = 0; i < 4; ++i) {
      int wc = i * 4 + w;
      int row = wc * 8 + lr;
      int g = lg ^ (row & 7);
      GLDS(Pg + (size_t)(m0 + row) * W + kt * 64 + g * 8, As + wc * 512);
      if (i < 2)
        GLDS(ETb + (size_t)(n0 + row) * VPAD + cbase + kt * 64 + g * 8, Bs + wc * 512);
    }
    __syncthreads();
    #pragma unroll
    for (int kk = 0; kk < 2; ++kk) {
      bf16x8 a[2], b[4];
      #pragma unroll
      for (int mi = 0; mi < 2; ++mi) {
        int arow = w * 32 + mi * 16 + l15;
        int slot = (kk * 4 + quad) ^ (arow & 7);
        a[mi] = *(const bf16x8*)&As[arow * 64 + slot * 8];
      }
      #pragma unroll
      for (int ni = 0; ni < 4; ++ni) {
        int brow = ni * 16 + l15;
        int slot = (kk * 4 + quad) ^ (brow & 7);
        b[ni] = *(const bf16x8*)&Bs[brow * 64 + slot * 8];
      }
      #pragma unroll
      for (int mi = 0; mi < 2; ++mi)
        #pragma unroll
        for (int ni = 0; ni < 4; ++ni)
          acc[mi][ni] = __builtin_amdgcn_mfma_f32_16x16x32_bf16(a[mi], b[ni], acc[mi][ni], 0, 0, 0);
    }
    __syncthreads();
  }
  #pragma unroll
  for (int mi = 0; mi < 2; ++mi)
    #pragma unroll
    for (int ni = 0; ni < 4; ++ni)
      #pragma unroll
      for (int r = 0; r < 4; ++r) {
        int m = m0 + w * 32 + mi * 16 + quad * 4 + r;
        int d = n0 + ni * 16 + l15;
        Out[(size_t)m * DD + d] += acc[mi][ni][r];
      }
}

// ------------------------------------------- k4: out = out/l + q   (in place)
__global__ __launch_bounds__(256) void k_fin(float* __restrict__ Out,
                                             const float* __restrict__ Lacc,
                                             const u16* __restrict__ Qb) {
  int idx = blockIdx.x * 256 + threadIdx.x;
  int m = idx >> 7;
  int d4 = (idx & 127) * 4;
  float inv = 1.f / Lacc[m];
  f32x4 ov = *(const f32x4*)(Out + (size_t)m * DD + d4);
  const u16* qp = Qb + (size_t)m * DD + d4;
  f32x4 r;
  #pragma unroll
  for (int i = 0; i < 4; ++i) r[i] = ov[i] * inv + bf2f(qp[i]);
  *(f32x4*)(Out + (size_t)m * DD + d4) = r;
}

extern "C" void kernel_launch(void* const* d_in, const int* in_sizes, int n_in,
                              void* d_out, int out_size, void* d_ws, size_t ws_size,
                              hipStream_t stream) {
  const float* x  = (const float*)d_in[0];
  const float* Wp = (const float*)d_in[1];
  const float* E  = (const float*)d_in[2];
  float* out = (float*)d_out;
  char* ws = (char*)d_ws;
  u16*   Qb   = (u16*)(ws + WS_Q);
  u16*   Eb   = (u16*)(ws + WS_EB);
  u16*   ETb  = (u16*)(ws + WS_ET);
  float* Lacc = (float*)(ws + WS_LACC);
  u16*   Pc   = (u16*)(ws + WS_P);

  // pick P-chunk width by workspace size (W=640 path needs only 30.4 MB)
  int W = 640;
  if (ws_size >= (size_t)WS_P + (size_t)MM * 2560 * 2) W = 2560;
  else if (ws_size >= (size_t)WS_P + (size_t)MM * 1280 * 2) W = 1280;
  int nch = VPAD / W;

  k_eprep<<<dim3(VPAD / 64, DD / 64), 256, 0, stream>>>(E, Eb, ETb, out, Lacc);
  k_gemm1<<<dim3(MM / 64, DD / 64), 256, 0, stream>>>(x, Wp, Qb);
  for (int c = 0; c < nch; ++c) {
    k_s <<<dim3(MM / 128, W / 128), 256, 0, stream>>>(Qb, Eb, Pc, Lacc, c * W, W);
    k_pv<<<dim3(MM / 128, DD / 64), 256, 0, stream>>>(Pc, ETb, out, c * W, W);
  }
  k_fin<<<dim3(MM * DD / 4 / 256), 256, 0, stream>>>(out, Lacc, Qb);
}

// Round 3
// 421.605 us; speedup vs baseline: 1.1167x; 1.0937x over previous
//
#include <hip/hip_runtime.h>
#include <hip/hip_bf16.h>

typedef unsigned short u16;
typedef unsigned int u32;
typedef __bf16 bf16x8 __attribute__((ext_vector_type(8)));
typedef u16 u16x8 __attribute__((ext_vector_type(8)));
typedef float f32x4 __attribute__((ext_vector_type(4)));

#define MM   4096      // B*L
#define CC   4000      // char vocab (K of gemm1)
#define KP   4096      // padded K for gemm1 fast path
#define DD   512       // d_vec
#define VV   10000     // emb rows
#define VPAD 10240     // 80*128, zero-padded tail

// ws layout (bytes)
#define WS_Q    0u          // Qb   bf16 [4096][512]    = 4,194,304
#define WS_EB   4194304u    // Eb   bf16 [10240][512]   = 10,485,760
#define WS_ET   14680064u   // ET   bf16 [512][10240]   = 10,485,760
#define WS_LACC 25165824u   // Lacc f32  [4096]         = 16,384
#define WS_P    25182208u   // P chunk region; ALSO (earlier phase) Xb/Wb/Qacc:
#define OFF_XB  0u          //   Xb bf16 [4096][4096] = 33,554,432
#define OFF_WB  33554432u   //   Wb bf16 [512][4096]  =  4,194,304
#define OFF_QA  37748736u   //   Qacc f32 [2][4096][512] = 16,777,216
#define FAST_NEED (WS_P + OFF_QA + 16777216u)   // 79,708,160

__device__ __forceinline__ u16 f2bf(float f) {
  u32 u = __builtin_bit_cast(u32, f);
  return (u16)((u + 0x7FFFu + ((u >> 16) & 1u)) >> 16);  // RNE
}
__device__ __forceinline__ float bf2f(u16 h) {
  u32 u = (u32)h << 16;
  return __builtin_bit_cast(float, u);
}

// async global->LDS, 16B per lane; LDS dest is wave-uniform base + lane*16
#define GLDS(gp, lp) __builtin_amdgcn_global_load_lds( \
    (const __attribute__((address_space(1))) void*)(gp), \
    (__attribute__((address_space(3))) void*)(lp), 16, 0, 0)

// ---------------------------------------------------------------- k0: E prep
__global__ __launch_bounds__(256) void k_eprep(const float* __restrict__ E,
                                               u16* __restrict__ Eb,
                                               u16* __restrict__ ETb,
                                               float* __restrict__ Out,
                                               float* __restrict__ Lacc) {
  __shared__ u16 st[64 * 65];
  int tid = threadIdx.x;
  { // zero d_out (4096*512 f32) and Lacc (4096 f32)
    int bid = blockIdx.x * 8 + blockIdx.y;
    f32x4 z = {0.f, 0.f, 0.f, 0.f};
    #pragma unroll
    for (int rep = 0; rep < 2; ++rep) {
      int id = bid * 256 + tid + rep * 327680;
      if (id < 524288)      *(f32x4*)(Out + (size_t)id * 4) = z;
      else if (id < 525312) *(f32x4*)(Lacc + (size_t)(id - 524288) * 4) = z;
    }
  }
  int v0 = blockIdx.x * 64, d0 = blockIdx.y * 64;
  int r = tid >> 2, seg = tid & 3;
  u16 h[16];
  int v = v0 + r;
  if (v < VV) {
    const float* src = E + (size_t)v * DD + d0 + seg * 16;
    #pragma unroll
    for (int j = 0; j < 4; ++j) {
      float4 t = *(const float4*)(src + j * 4);
      h[4*j+0] = f2bf(t.x); h[4*j+1] = f2bf(t.y); h[4*j+2] = f2bf(t.z); h[4*j+3] = f2bf(t.w);
    }
  } else {
    #pragma unroll
    for (int j = 0; j < 16; ++j) h[j] = 0;
  }
  {
    u16x8 p0, p1;
    #pragma unroll
    for (int j = 0; j < 8; ++j) { p0[j] = h[j]; p1[j] = h[8+j]; }
    u16* dst = Eb + (size_t)v * DD + d0 + seg * 16;
    *(u16x8*)dst = p0; *(u16x8*)(dst + 8) = p1;
  }
  #pragma unroll
  for (int j = 0; j < 16; ++j) st[r * 65 + seg * 16 + j] = h[j];
  __syncthreads();
  {
    u16 g[16];
    #pragma unroll
    for (int j = 0; j < 16; ++j) g[j] = st[(seg * 16 + j) * 65 + r];
    u16x8 p0, p1;
    #pragma unroll
    for (int j = 0; j < 8; ++j) { p0[j] = g[j]; p1[j] = g[8+j]; }
    u16* dst = ETb + (size_t)(d0 + r) * VPAD + v0 + seg * 16;
    *(u16x8*)dst = p0; *(u16x8*)(dst + 8) = p1;
  }
}

// --------------------------------- k_conv: X,W f32 -> bf16, K padded to 4096
// row-per-block; memory-bound. rows [0,4096)=X, [4096,4608)=W.
__global__ __launch_bounds__(256) void k_conv(const float* __restrict__ X,
                                              const float* __restrict__ Wp,
                                              u16* __restrict__ Xb,
                                              u16* __restrict__ Wb) {
  int row = blockIdx.x;
  int t = threadIdx.x;
  const float* src;
  u16* dst;
  if (row < MM) { src = X + (size_t)row * CC; dst = Xb + (size_t)row * KP; }
  else { src = Wp + (size_t)(row - MM) * CC; dst = Wb + (size_t)(row - MM) * KP; }
  int c0 = t * 16;
  u16 h[16];
  if (c0 + 16 <= CC) {            // 4000 % 16 == 0: all-or-nothing
    #pragma unroll
    for (int j = 0; j < 4; ++j) {
      float4 v = *(const float4*)(src + c0 + j * 4);
      h[4*j+0] = f2bf(v.x); h[4*j+1] = f2bf(v.y); h[4*j+2] = f2bf(v.z); h[4*j+3] = f2bf(v.w);
    }
  } else {
    #pragma unroll
    for (int j = 0; j < 16; ++j) h[j] = 0;
  }
  u16x8 p0, p1;
  #pragma unroll
  for (int j = 0; j < 8; ++j) { p0[j] = h[j]; p1[j] = h[8+j]; }
  *(u16x8*)(dst + c0) = p0; *(u16x8*)(dst + c0 + 8) = p1;
}

// --------------------------------- k_g1: Qacc[z] = Xb @ Wb^T (partial K)
// m97 skeleton: 128x64 tile, BK=64, GLDS staging, XOR swizzle, split-K x2,
// NO conversions / ds_writes in the K-loop. Partials -> f32 (no atomics).
__global__ __launch_bounds__(256) void k_g1(const u16* __restrict__ Xb,
                                            const u16* __restrict__ Wb,
                                            float* __restrict__ Qacc) {
  __shared__ u16 As[128 * 64];   // 16 KB
  __shared__ u16 Bs[64 * 64];    // 8 KB
  int tid = threadIdx.x;
  int m0 = blockIdx.x * 128;
  int n0 = blockIdx.y * 64;
  int kt0 = blockIdx.z * 32;
  int w = tid >> 6, l = tid & 63;
  int l15 = l & 15, quad = l >> 4;
  int lr = l >> 3, lg = l & 7;
  f32x4 acc[2][4] = {};

  for (int kt = kt0; kt < kt0 + 32; ++kt) {
    #pragma unroll
    for (int i = 0; i < 4; ++i) {
      int wc = i * 4 + w;
      int row = wc * 8 + lr;
      int g = lg ^ (row & 7);
      GLDS(Xb + (size_t)(m0 + row) * KP + kt * 64 + g * 8, As + wc * 512);
      if (i < 2)
        GLDS(Wb + (size_t)(n0 + row) * KP + kt * 64 + g * 8, Bs + wc * 512);
    }
    __syncthreads();
    #pragma unroll
    for (int kk = 0; kk < 2; ++kk) {
      bf16x8 a[2], b[4];
      #pragma unroll
      for (int mi = 0; mi < 2; ++mi) {
        int arow = w * 32 + mi * 16 + l15;
        int slot = (kk * 4 + quad) ^ (arow & 7);
        a[mi] = *(const bf16x8*)&As[arow * 64 + slot * 8];
      }
      #pragma unroll
      for (int ni = 0; ni < 4; ++ni) {
        int brow = ni * 16 + l15;
        int slot = (kk * 4 + quad) ^ (brow & 7);
        b[ni] = *(const bf16x8*)&Bs[brow * 64 + slot * 8];
      }
      #pragma unroll
      for (int mi = 0; mi < 2; ++mi)
        #pragma unroll
        for (int ni = 0; ni < 4; ++ni)
          acc[mi][ni] = __builtin_amdgcn_mfma_f32_16x16x32_bf16(a[mi], b[ni], acc[mi][ni], 0, 0, 0);
    }
    __syncthreads();
  }
  float* dst = Qacc + (size_t)blockIdx.z * (MM * DD);
  #pragma unroll
  for (int mi = 0; mi < 2; ++mi)
    #pragma unroll
    for (int ni = 0; ni < 4; ++ni)
      #pragma unroll
      for (int r = 0; r < 4; ++r) {
        int m = m0 + w * 32 + mi * 16 + quad * 4 + r;
        int d = n0 + ni * 16 + l15;
        dst[(size_t)m * DD + d] = acc[mi][ni][r];
      }
}

// --------------------------------- k_tanh: Qb = bf16(tanh(Qacc0 + Qacc1))
__global__ __launch_bounds__(256) void k_tanh(const float* __restrict__ Qacc,
                                              u16* __restrict__ Qb) {
  int idx = blockIdx.x * 256 + threadIdx.x;   // 8 elems/thread
  size_t base = (size_t)idx * 8;
  f32x4 a0 = *(const f32x4*)(Qacc + base);
  f32x4 a1 = *(const f32x4*)(Qacc + base + 4);
  f32x4 b0 = *(const f32x4*)(Qacc + (size_t)MM * DD + base);
  f32x4 b1 = *(const f32x4*)(Qacc + (size_t)MM * DD + base + 4);
  u16x8 p;
  #pragma unroll
  for (int j = 0; j < 4; ++j) p[j] = f2bf(tanhf(a0[j] + b0[j]));
  #pragma unroll
  for (int j = 0; j < 4; ++j) p[4 + j] = f2bf(tanhf(a1[j] + b1[j]));
  *(u16x8*)(Qb + base) = p;
}

// ---------------------------------------------------- k1 (FALLBACK): q = tanh(x @ W^T)
__global__ __launch_bounds__(256) void k_gemm1(const float* __restrict__ X,
                                               const float* __restrict__ W,
                                               u16* __restrict__ Qb) {
  __shared__ u16 xs[64 * 64];
  __shared__ u16 wst[64 * 64];
  int tid = threadIdx.x;
  int m0 = blockIdx.x * 64;
  int n0 = blockIdx.y * 64;
  int srow = tid >> 2;
  int sseg = tid & 3;
  int r7 = srow & 7;
  const float* xsrc = X + (size_t)(m0 + srow) * CC + sseg * 16;
  const float* wsrc = W + (size_t)(n0 + srow) * CC + sseg * 16;
  int lane = tid & 63;
  int wv = tid >> 6;
  int l15 = lane & 15, quad = lane >> 4;
  f32x4 acc[4] = {};

  for (int kt = 0; kt < 63; ++kt) {
    int cbase = kt * 64 + sseg * 16;
    float xv[16], wf[16];
    if (cbase + 16 <= CC) {
      #pragma unroll
      for (int j = 0; j < 4; ++j) {
        float4 tx = *(const float4*)(xsrc + kt * 64 + j * 4);
        float4 tw = *(const float4*)(wsrc + kt * 64 + j * 4);
        xv[4*j+0] = tx.x; xv[4*j+1] = tx.y; xv[4*j+2] = tx.z; xv[4*j+3] = tx.w;
        wf[4*j+0] = tw.x; wf[4*j+1] = tw.y; wf[4*j+2] = tw.z; wf[4*j+3] = tw.w;
      }
    } else {
      #pragma unroll
      for (int j = 0; j < 16; ++j) { xv[j] = 0.f; wf[j] = 0.f; }
    }
    __syncthreads();
    #pragma unroll
    for (int j = 0; j < 2; ++j) {
      int g = (sseg * 2 + j) ^ r7;
      u16x8 px, pw;
      #pragma unroll
      for (int e = 0; e < 8; ++e) { px[e] = f2bf(xv[8*j+e]); pw[e] = f2bf(wf[8*j+e]); }
      *(u16x8*)&xs[srow * 64 + (g << 3)] = px;
      *(u16x8*)&wst[srow * 64 + (g << 3)] = pw;
    }
    __syncthreads();
    #pragma unroll
    for (int kk = 0; kk < 2; ++kk) {
      int arow = 16 * wv + l15;
      int ga = (kk * 4 + quad) ^ (arow & 7);
      bf16x8 a = *(const bf16x8*)&xs[arow * 64 + (ga << 3)];
      #pragma unroll
      for (int nb = 0; nb < 4; ++nb) {
        int brow = 16 * nb + l15;
        int gb = (kk * 4 + quad) ^ (brow & 7);
        bf16x8 b = *(const bf16x8*)&wst[brow * 64 + (gb << 3)];
        acc[nb] = __builtin_amdgcn_mfma_f32_16x16x32_bf16(a, b, acc[nb], 0, 0, 0);
      }
    }
  }
  #pragma unroll
  for (int nb = 0; nb < 4; ++nb) {
    int d = n0 + 16 * nb + l15;
    #pragma unroll
    for (int r = 0; r < 4; ++r) {
      int m = m0 + 16 * wv + 4 * quad + r;
      Qb[(size_t)m * DD + d] = f2bf(tanhf(acc[nb][r]));
    }
  }
}

// -------------------------------------- k2: P = exp(q @ E^T), l += rowsum(P)
__global__ __launch_bounds__(256) void k_s(const u16* __restrict__ Qb,
                                           const u16* __restrict__ Eb,
                                           u16* __restrict__ Pg,
                                           float* __restrict__ Lacc,
                                           int cbase, int W) {
  __shared__ u16 As[128 * 64];
  __shared__ u16 Bs[128 * 64];
  int tid = threadIdx.x;
  int m0 = blockIdx.x * 128;
  int n0 = blockIdx.y * 128;
  int w = tid >> 6, l = tid & 63;
  int l15 = l & 15, quad = l >> 4;
  int mhalf = w >> 1, nhalf = w & 1;
  int lr = l >> 3, lg = l & 7;
  f32x4 acc[4][4] = {};

  for (int kt = 0; kt < 8; ++kt) {
    #pragma unroll
    for (int i = 0; i < 4; ++i) {
      int wc = i * 4 + w;
      int row = wc * 8 + lr;
      int g = lg ^ (row & 7);
      GLDS(Qb + (size_t)(m0 + row) * DD + kt * 64 + g * 8, As + wc * 512);
      GLDS(Eb + (size_t)(cbase + n0 + row) * DD + kt * 64 + g * 8, Bs + wc * 512);
    }
    __syncthreads();
    #pragma unroll
    for (int kk = 0; kk < 2; ++kk) {
      bf16x8 a[4], b[4];
      #pragma unroll
      for (int mi = 0; mi < 4; ++mi) {
        int arow = mhalf * 64 + mi * 16 + l15;
        int slot = (kk * 4 + quad) ^ (arow & 7);
        a[mi] = *(const bf16x8*)&As[arow * 64 + slot * 8];
      }
      #pragma unroll
      for (int ni = 0; ni < 4; ++ni) {
        int brow = nhalf * 64 + ni * 16 + l15;
        int slot = (kk * 4 + quad) ^ (brow & 7);
        b[ni] = *(const bf16x8*)&Bs[brow * 64 + slot * 8];
      }
      #pragma unroll
      for (int mi = 0; mi < 4; ++mi)
        #pragma unroll
        for (int ni = 0; ni < 4; ++ni)
          acc[mi][ni] = __builtin_amdgcn_mfma_f32_16x16x32_bf16(a[mi], b[ni], acc[mi][ni], 0, 0, 0);
    }
    __syncthreads();
  }

  float rs[4][4] = {};
  #pragma unroll
  for (int mi = 0; mi < 4; ++mi) {
    #pragma unroll
    for (int ni = 0; ni < 4; ++ni) {
      int ncol = n0 + nhalf * 64 + ni * 16 + l15;
      bool ok = (cbase + ncol) < VV;
      #pragma unroll
      for (int r = 0; r < 4; ++r) {
        float p = ok ? __expf(acc[mi][ni][r]) : 0.f;
        rs[mi][r] += p;
        int m = m0 + mhalf * 64 + mi * 16 + quad * 4 + r;
        Pg[(size_t)m * W + ncol] = f2bf(p);
      }
    }
  }
  #pragma unroll
  for (int mi = 0; mi < 4; ++mi)
    #pragma unroll
    for (int r = 0; r < 4; ++r) {
      float v = rs[mi][r];
      v += __shfl_xor(v, 1, 16);
      v += __shfl_xor(v, 2, 16);
      v += __shfl_xor(v, 4, 16);
      v += __shfl_xor(v, 8, 16);
      if (l15 == 0)
        atomicAdd(&Lacc[m0 + mhalf * 64 + mi * 16 + quad * 4 + r], v);
    }
}

// -------------------------------------- k3: Out += P @ E   (RMW f32)
__global__ __launch_bounds__(256) void k_pv(const u16* __restrict__ Pg,
                                            const u16* __restrict__ ETb,
                                            float* __restrict__ Out,
                                            int cbase, int W) {
  __shared__ u16 As[128 * 64];
  __shared__ u16 Bs[64 * 64];
  int tid = threadIdx.x;
  int m0 = blockIdx.x * 128;
  int n0 = blockIdx.y * 64;
  int w = tid >> 6, l = tid & 63;
  int l15 = l & 15, quad = l >> 4;
  int lr = l >> 3, lg = l & 7;
  int iters = W >> 6;
  f32x4 acc[2][4] = {};

  for (int kt = 0; kt < iters; ++kt) {
    #pragma unroll
    for (int i = 0; i < 4; ++i) {
      int wc = i * 4 + w;
      int row = wc * 8 + lr;
      int g = lg ^ (row & 7);
      GLDS(Pg + (size_t)(m0 + row) * W + kt * 64 + g * 8, As + wc * 512);
      if (i < 2)
        GLDS(ETb + (size_t)(n0 + row) * VPAD + cbase + kt * 64 + g * 8, Bs + wc * 512);
    }
    __syncthreads();
    #pragma unroll
    for (int kk = 0; kk < 2; ++kk) {
      bf16x8 a[2], b[4];
      #pragma unroll
      for (int mi = 0; mi < 2; ++mi) {
        int arow = w * 32 + mi * 16 + l15;
        int slot = (kk * 4 + quad) ^ (arow & 7);
        a[mi] = *(const bf16x8*)&As[arow * 64 + slot * 8];
      }
      #pragma unroll
      for (int ni = 0; ni < 4; ++ni) {
        int brow = ni * 16 + l15;
        int slot = (kk * 4 + quad) ^ (brow & 7);
        b[ni] = *(const bf16x8*)&Bs[brow * 64 + slot * 8];
      }
      #pragma unroll
      for (int mi = 0; mi < 2; ++mi)
        #pragma unroll
        for (int ni = 0; ni < 4; ++ni)
          acc[mi][ni] = __builtin_amdgcn_mfma_f32_16x16x32_bf16(a[mi], b[ni], acc[mi][ni], 0, 0, 0);
    }
    __syncthreads();
  }
  #pragma unroll
  for (int mi = 0; mi < 2; ++mi)
    #pragma unroll
    for (int ni = 0; ni < 4; ++ni)
      #pragma unroll
      for (int r = 0; r < 4; ++r) {
        int m = m0 + w * 32 + mi * 16 + quad * 4 + r;
        int d = n0 + ni * 16 + l15;
        Out[(size_t)m * DD + d] += acc[mi][ni][r];
      }
}

// ------------------------------------------- k4: out = out/l + q   (in place)
__global__ __launch_bounds__(256) void k_fin(float* __restrict__ Out,
                                             const float* __restrict__ Lacc,
                                             const u16* __restrict__ Qb) {
  int idx = blockIdx.x * 256 + threadIdx.x;
  int m = idx >> 7;
  int d4 = (idx & 127) * 4;
  float inv = 1.f / Lacc[m];
  f32x4 ov = *(const f32x4*)(Out + (size_t)m * DD + d4);
  const u16* qp = Qb + (size_t)m * DD + d4;
  f32x4 r;
  #pragma unroll
  for (int i = 0; i < 4; ++i) r[i] = ov[i] * inv + bf2f(qp[i]);
  *(f32x4*)(Out + (size_t)m * DD + d4) = r;
}

extern "C" void kernel_launch(void* const* d_in, const int* in_sizes, int n_in,
                              void* d_out, int out_size, void* d_ws, size_t ws_size,
                              hipStream_t stream) {
  const float* x  = (const float*)d_in[0];
  const float* Wp = (const float*)d_in[1];
  const float* E  = (const float*)d_in[2];
  float* out = (float*)d_out;
  char* ws = (char*)d_ws;
  u16*   Qb   = (u16*)(ws + WS_Q);
  u16*   Eb   = (u16*)(ws + WS_EB);
  u16*   ETb  = (u16*)(ws + WS_ET);
  float* Lacc = (float*)(ws + WS_LACC);
  u16*   Pc   = (u16*)(ws + WS_P);
  u16*   Xb   = (u16*)(ws + WS_P + OFF_XB);
  u16*   Wb   = (u16*)(ws + WS_P + OFF_WB);
  float* Qacc = (float*)(ws + WS_P + OFF_QA);

  int W = 640;
  if (ws_size >= (size_t)WS_P + (size_t)MM * 2560 * 2) W = 2560;
  else if (ws_size >= (size_t)WS_P + (size_t)MM * 1280 * 2) W = 1280;
  int nch = VPAD / W;
  bool fast = ws_size >= (size_t)FAST_NEED;

  k_eprep<<<dim3(VPAD / 64, DD / 64), 256, 0, stream>>>(E, Eb, ETb, out, Lacc);
  if (fast) {
    k_conv<<<dim3(MM + DD), 256, 0, stream>>>(x, Wp, Xb, Wb);
    k_g1<<<dim3(MM / 128, DD / 64, 2), 256, 0, stream>>>(Xb, Wb, Qacc);
    k_tanh<<<dim3(MM * DD / 8 / 256), 256, 0, stream>>>(Qacc, Qb);
  } else {
    k_gemm1<<<dim3(MM / 64, DD / 64), 256, 0, stream>>>(x, Wp, Qb);
  }
  for (int c = 0; c < nch; ++c) {
    k_s <<<dim3(MM / 128, W / 128), 256, 0, stream>>>(Qb, Eb, Pc, Lacc, c * W, W);
    k_pv<<<dim3(MM / 128, DD / 64), 256, 0, stream>>>(Pc, ETb, out, c * W, W);
  }
  k_fin<<<dim3(MM * DD / 4 / 256), 256, 0, stream>>>(out, Lacc, Qb);
}

// Round 4
// 297.805 us; speedup vs baseline: 1.5809x; 1.4157x over previous
//
#include <hip/hip_runtime.h>
#include <hip/hip_bf16.h>

typedef unsigned short u16;
typedef unsigned int u32;
typedef __bf16 bf16x8 __attribute__((ext_vector_type(8)));
typedef u16 u16x8 __attribute__((ext_vector_type(8)));
typedef float f32x4 __attribute__((ext_vector_type(4)));

#define MM   4096      // B*L
#define CC   4000      // char vocab (K of gemm1)
#define KP   4096      // padded K for gemm1 fast path
#define DD   512       // d_vec
#define VV   10000     // emb rows
#define VPAD 10240     // 80*128, zero-padded tail

// ws layout (bytes)
#define WS_Q    0u          // Qb   bf16 [4096][512]    = 4,194,304
#define WS_EB   4194304u    // Eb   bf16 [10240][512]   = 10,485,760
#define WS_ET   14680064u   // ET   bf16 [512][10240]   = 10,485,760
#define WS_LACC 25165824u   // Lacc f32  [4096]         = 16,384
#define WS_P    25182208u   // P bf16 [4096][VPAD] = 83,886,080 (full-P fast path)
                            // ALSO aliased (earlier, dead before k_s): Xb/Wb/Qacc
#define OFF_XB  0u          //   Xb bf16 [4096][4096] = 33,554,432
#define OFF_WB  33554432u   //   Wb bf16 [512][4096]  =  4,194,304
#define OFF_QA  37748736u   //   Qacc f32 [2][4096][512] = 16,777,216
#define FAST_NEED (WS_P + OFF_QA + 16777216u)      // 79,708,160 (gemm1 fast path)
#define WS_PACC 109068288u  // Pacc f32 [8][4096][512] = 67,108,864
#define FULLP_NEED (WS_PACC + 67108864u)           // 176,177,152 (full-P attention)

__device__ __forceinline__ u16 f2bf(float f) {
  u32 u = __builtin_bit_cast(u32, f);
  return (u16)((u + 0x7FFFu + ((u >> 16) & 1u)) >> 16);  // RNE
}
__device__ __forceinline__ float bf2f(u16 h) {
  u32 u = (u32)h << 16;
  return __builtin_bit_cast(float, u);
}

// async global->LDS, 16B per lane; LDS dest is wave-uniform base + lane*16
#define GLDS(gp, lp) __builtin_amdgcn_global_load_lds( \
    (const __attribute__((address_space(1))) void*)(gp), \
    (__attribute__((address_space(3))) void*)(lp), 16, 0, 0)

// ---------------------------------------------------------------- k0: E prep
__global__ __launch_bounds__(256) void k_eprep(const float* __restrict__ E,
                                               u16* __restrict__ Eb,
                                               u16* __restrict__ ETb,
                                               float* __restrict__ Out,
                                               float* __restrict__ Lacc) {
  __shared__ u16 st[64 * 65];
  int tid = threadIdx.x;
  { // zero d_out (4096*512 f32) and Lacc (4096 f32)
    int bid = blockIdx.x * 8 + blockIdx.y;
    f32x4 z = {0.f, 0.f, 0.f, 0.f};
    #pragma unroll
    for (int rep = 0; rep < 2; ++rep) {
      int id = bid * 256 + tid + rep * 327680;
      if (id < 524288)      *(f32x4*)(Out + (size_t)id * 4) = z;
      else if (id < 525312) *(f32x4*)(Lacc + (size_t)(id - 524288) * 4) = z;
    }
  }
  int v0 = blockIdx.x * 64, d0 = blockIdx.y * 64;
  int r = tid >> 2, seg = tid & 3;
  u16 h[16];
  int v = v0 + r;
  if (v < VV) {
    const float* src = E + (size_t)v * DD + d0 + seg * 16;
    #pragma unroll
    for (int j = 0; j < 4; ++j) {
      float4 t = *(const float4*)(src + j * 4);
      h[4*j+0] = f2bf(t.x); h[4*j+1] = f2bf(t.y); h[4*j+2] = f2bf(t.z); h[4*j+3] = f2bf(t.w);
    }
  } else {
    #pragma unroll
    for (int j = 0; j < 16; ++j) h[j] = 0;
  }
  {
    u16x8 p0, p1;
    #pragma unroll
    for (int j = 0; j < 8; ++j) { p0[j] = h[j]; p1[j] = h[8+j]; }
    u16* dst = Eb + (size_t)v * DD + d0 + seg * 16;
    *(u16x8*)dst = p0; *(u16x8*)(dst + 8) = p1;
  }
  #pragma unroll
  for (int j = 0; j < 16; ++j) st[r * 65 + seg * 16 + j] = h[j];
  __syncthreads();
  {
    u16 g[16];
    #pragma unroll
    for (int j = 0; j < 16; ++j) g[j] = st[(seg * 16 + j) * 65 + r];
    u16x8 p0, p1;
    #pragma unroll
    for (int j = 0; j < 8; ++j) { p0[j] = g[j]; p1[j] = g[8+j]; }
    u16* dst = ETb + (size_t)(d0 + r) * VPAD + v0 + seg * 16;
    *(u16x8*)dst = p0; *(u16x8*)(dst + 8) = p1;
  }
}

// --------------------------------- k_conv: X,W f32 -> bf16, K padded to 4096
__global__ __launch_bounds__(256) void k_conv(const float* __restrict__ X,
                                              const float* __restrict__ Wp,
                                              u16* __restrict__ Xb,
                                              u16* __restrict__ Wb) {
  int row = blockIdx.x;
  int t = threadIdx.x;
  const float* src;
  u16* dst;
  if (row < MM) { src = X + (size_t)row * CC; dst = Xb + (size_t)row * KP; }
  else { src = Wp + (size_t)(row - MM) * CC; dst = Wb + (size_t)(row - MM) * KP; }
  int c0 = t * 16;
  u16 h[16];
  if (c0 + 16 <= CC) {
    #pragma unroll
    for (int j = 0; j < 4; ++j) {
      float4 v = *(const float4*)(src + c0 + j * 4);
      h[4*j+0] = f2bf(v.x); h[4*j+1] = f2bf(v.y); h[4*j+2] = f2bf(v.z); h[4*j+3] = f2bf(v.w);
    }
  } else {
    #pragma unroll
    for (int j = 0; j < 16; ++j) h[j] = 0;
  }
  u16x8 p0, p1;
  #pragma unroll
  for (int j = 0; j < 8; ++j) { p0[j] = h[j]; p1[j] = h[8+j]; }
  *(u16x8*)(dst + c0) = p0; *(u16x8*)(dst + c0 + 8) = p1;
}

// --------------------------------- k_g1: Qacc[z] = Xb @ Wb^T (partial K)
__global__ __launch_bounds__(256) void k_g1(const u16* __restrict__ Xb,
                                            const u16* __restrict__ Wb,
                                            float* __restrict__ Qacc) {
  __shared__ u16 As[128 * 64];
  __shared__ u16 Bs[64 * 64];
  int tid = threadIdx.x;
  int m0 = blockIdx.x * 128;
  int n0 = blockIdx.y * 64;
  int kt0 = blockIdx.z * 32;
  int w = tid >> 6, l = tid & 63;
  int l15 = l & 15, quad = l >> 4;
  int lr = l >> 3, lg = l & 7;
  f32x4 acc[2][4] = {};

  for (int kt = kt0; kt < kt0 + 32; ++kt) {
    #pragma unroll
    for (int i = 0; i < 4; ++i) {
      int wc = i * 4 + w;
      int row = wc * 8 + lr;
      int g = lg ^ (row & 7);
      GLDS(Xb + (size_t)(m0 + row) * KP + kt * 64 + g * 8, As + wc * 512);
      if (i < 2)
        GLDS(Wb + (size_t)(n0 + row) * KP + kt * 64 + g * 8, Bs + wc * 512);
    }
    __syncthreads();
    #pragma unroll
    for (int kk = 0; kk < 2; ++kk) {
      bf16x8 a[2], b[4];
      #pragma unroll
      for (int mi = 0; mi < 2; ++mi) {
        int arow = w * 32 + mi * 16 + l15;
        int slot = (kk * 4 + quad) ^ (arow & 7);
        a[mi] = *(const bf16x8*)&As[arow * 64 + slot * 8];
      }
      #pragma unroll
      for (int ni = 0; ni < 4; ++ni) {
        int brow = ni * 16 + l15;
        int slot = (kk * 4 + quad) ^ (brow & 7);
        b[ni] = *(const bf16x8*)&Bs[brow * 64 + slot * 8];
      }
      #pragma unroll
      for (int mi = 0; mi < 2; ++mi)
        #pragma unroll
        for (int ni = 0; ni < 4; ++ni)
          acc[mi][ni] = __builtin_amdgcn_mfma_f32_16x16x32_bf16(a[mi], b[ni], acc[mi][ni], 0, 0, 0);
    }
    __syncthreads();
  }
  float* dst = Qacc + (size_t)blockIdx.z * (MM * DD);
  #pragma unroll
  for (int mi = 0; mi < 2; ++mi)
    #pragma unroll
    for (int ni = 0; ni < 4; ++ni)
      #pragma unroll
      for (int r = 0; r < 4; ++r) {
        int m = m0 + w * 32 + mi * 16 + quad * 4 + r;
        int d = n0 + ni * 16 + l15;
        dst[(size_t)m * DD + d] = acc[mi][ni][r];
      }
}

// --------------------------------- k_tanh: Qb = bf16(tanh(Qacc0 + Qacc1))
__global__ __launch_bounds__(256) void k_tanh(const float* __restrict__ Qacc,
                                              u16* __restrict__ Qb) {
  int idx = blockIdx.x * 256 + threadIdx.x;
  size_t base = (size_t)idx * 8;
  f32x4 a0 = *(const f32x4*)(Qacc + base);
  f32x4 a1 = *(const f32x4*)(Qacc + base + 4);
  f32x4 b0 = *(const f32x4*)(Qacc + (size_t)MM * DD + base);
  f32x4 b1 = *(const f32x4*)(Qacc + (size_t)MM * DD + base + 4);
  u16x8 p;
  #pragma unroll
  for (int j = 0; j < 4; ++j) p[j] = f2bf(tanhf(a0[j] + b0[j]));
  #pragma unroll
  for (int j = 0; j < 4; ++j) p[4 + j] = f2bf(tanhf(a1[j] + b1[j]));
  *(u16x8*)(Qb + base) = p;
}

// ---------------------------------------------------- k1 (FALLBACK): q = tanh(x @ W^T)
__global__ __launch_bounds__(256) void k_gemm1(const float* __restrict__ X,
                                               const float* __restrict__ W,
                                               u16* __restrict__ Qb) {
  __shared__ u16 xs[64 * 64];
  __shared__ u16 wst[64 * 64];
  int tid = threadIdx.x;
  int m0 = blockIdx.x * 64;
  int n0 = blockIdx.y * 64;
  int srow = tid >> 2;
  int sseg = tid & 3;
  int r7 = srow & 7;
  const float* xsrc = X + (size_t)(m0 + srow) * CC + sseg * 16;
  const float* wsrc = W + (size_t)(n0 + srow) * CC + sseg * 16;
  int lane = tid & 63;
  int wv = tid >> 6;
  int l15 = lane & 15, quad = lane >> 4;
  f32x4 acc[4] = {};

  for (int kt = 0; kt < 63; ++kt) {
    int cbase = kt * 64 + sseg * 16;
    float xv[16], wf[16];
    if (cbase + 16 <= CC) {
      #pragma unroll
      for (int j = 0; j < 4; ++j) {
        float4 tx = *(const float4*)(xsrc + kt * 64 + j * 4);
        float4 tw = *(const float4*)(wsrc + kt * 64 + j * 4);
        xv[4*j+0] = tx.x; xv[4*j+1] = tx.y; xv[4*j+2] = tx.z; xv[4*j+3] = tx.w;
        wf[4*j+0] = tw.x; wf[4*j+1] = tw.y; wf[4*j+2] = tw.z; wf[4*j+3] = tw.w;
      }
    } else {
      #pragma unroll
      for (int j = 0; j < 16; ++j) { xv[j] = 0.f; wf[j] = 0.f; }
    }
    __syncthreads();
    #pragma unroll
    for (int j = 0; j < 2; ++j) {
      int g = (sseg * 2 + j) ^ r7;
      u16x8 px, pw;
      #pragma unroll
      for (int e = 0; e < 8; ++e) { px[e] = f2bf(xv[8*j+e]); pw[e] = f2bf(wf[8*j+e]); }
      *(u16x8*)&xs[srow * 64 + (g << 3)] = px;
      *(u16x8*)&wst[srow * 64 + (g << 3)] = pw;
    }
    __syncthreads();
    #pragma unroll
    for (int kk = 0; kk < 2; ++kk) {
      int arow = 16 * wv + l15;
      int ga = (kk * 4 + quad) ^ (arow & 7);
      bf16x8 a = *(const bf16x8*)&xs[arow * 64 + (ga << 3)];
      #pragma unroll
      for (int nb = 0; nb < 4; ++nb) {
        int brow = 16 * nb + l15;
        int gb = (kk * 4 + quad) ^ (brow & 7);
        bf16x8 b = *(const bf16x8*)&wst[brow * 64 + (gb << 3)];
        acc[nb] = __builtin_amdgcn_mfma_f32_16x16x32_bf16(a, b, acc[nb], 0, 0, 0);
      }
    }
  }
  #pragma unroll
  for (int nb = 0; nb < 4; ++nb) {
    int d = n0 + 16 * nb + l15;
    #pragma unroll
    for (int r = 0; r < 4; ++r) {
      int m = m0 + 16 * wv + 4 * quad + r;
      Qb[(size_t)m * DD + d] = f2bf(tanhf(acc[nb][r]));
    }
  }
}

// -------------------------------------- k2: P = exp(q @ E^T), l += rowsum(P)
// 128x128 tile, BK=64, GLDS staging. Epilogue: exp + rowsum->Lacc + P staged
// through swizzled LDS for 16B-coalesced global stores (was 64x scalar 2B).
__global__ __launch_bounds__(256, 4) void k_s(const u16* __restrict__ Qb,
                                              const u16* __restrict__ Eb,
                                              u16* __restrict__ Pg,
                                              float* __restrict__ Lacc,
                                              int cbase, int W) {
  __shared__ u16 S[16384];       // As 128x64 | Bs 128x64; epilogue: P 128x128
  u16* As = S;
  u16* Bs = S + 8192;
  int tid = threadIdx.x;
  int m0 = blockIdx.x * 128;
  int n0 = blockIdx.y * 128;
  int w = tid >> 6, l = tid & 63;
  int l15 = l & 15, quad = l >> 4;
  int mhalf = w >> 1, nhalf = w & 1;
  int lr = l >> 3, lg = l & 7;
  f32x4 acc[4][4] = {};

  for (int kt = 0; kt < 8; ++kt) {
    #pragma unroll
    for (int i = 0; i < 4; ++i) {
      int wc = i * 4 + w;
      int row = wc * 8 + lr;
      int g = lg ^ (row & 7);
      GLDS(Qb + (size_t)(m0 + row) * DD + kt * 64 + g * 8, As + wc * 512);
      GLDS(Eb + (size_t)(cbase + n0 + row) * DD + kt * 64 + g * 8, Bs + wc * 512);
    }
    __syncthreads();
    #pragma unroll
    for (int kk = 0; kk < 2; ++kk) {
      bf16x8 a[4], b[4];
      #pragma unroll
      for (int mi = 0; mi < 4; ++mi) {
        int arow = mhalf * 64 + mi * 16 + l15;
        int slot = (kk * 4 + quad) ^ (arow & 7);
        a[mi] = *(const bf16x8*)&As[arow * 64 + slot * 8];
      }
      #pragma unroll
      for (int ni = 0; ni < 4; ++ni) {
        int brow = nhalf * 64 + ni * 16 + l15;
        int slot = (kk * 4 + quad) ^ (brow & 7);
        b[ni] = *(const bf16x8*)&Bs[brow * 64 + slot * 8];
      }
      #pragma unroll
      for (int mi = 0; mi < 4; ++mi)
        #pragma unroll
        for (int ni = 0; ni < 4; ++ni)
          acc[mi][ni] = __builtin_amdgcn_mfma_f32_16x16x32_bf16(a[mi], b[ni], acc[mi][ni], 0, 0, 0);
    }
    __syncthreads();
  }

  // epilogue: exp + mask; P -> swizzled LDS; rowsums
  float rs[4][4] = {};
  #pragma unroll
  for (int mi = 0; mi < 4; ++mi) {
    #pragma unroll
    for (int ni = 0; ni < 4; ++ni) {
      int colL = nhalf * 64 + ni * 16 + l15;
      bool ok = (cbase + n0 + colL) < VV;
      #pragma unroll
      for (int r = 0; r < 4; ++r) {
        int rowL = mhalf * 64 + mi * 16 + quad * 4 + r;
        float p = ok ? __expf(acc[mi][ni][r]) : 0.f;
        rs[mi][r] += p;
        S[rowL * 128 + (((colL >> 3) ^ (rowL & 15)) << 3) + (colL & 7)] = f2bf(p);
      }
    }
  }
  __syncthreads();
  { // coalesced P store: thread -> (row = tid/2, 64-col half = tid&1)
    int row = tid >> 1, h2 = tid & 1;
    size_t gbase = (size_t)(m0 + row) * W + n0 + h2 * 64;
    #pragma unroll
    for (int g = 0; g < 8; ++g) {
      int pg = (h2 * 8 + g) ^ (row & 15);
      u16x8 v = *(const u16x8*)&S[row * 128 + pg * 8];
      *(u16x8*)(Pg + gbase + g * 8) = v;
    }
  }
  #pragma unroll
  for (int mi = 0; mi < 4; ++mi)
    #pragma unroll
    for (int r = 0; r < 4; ++r) {
      float v = rs[mi][r];
      v += __shfl_xor(v, 1, 16);
      v += __shfl_xor(v, 2, 16);
      v += __shfl_xor(v, 4, 16);
      v += __shfl_xor(v, 8, 16);
      if (l15 == 0)
        atomicAdd(&Lacc[m0 + mhalf * 64 + mi * 16 + quad * 4 + r], v);
    }
}

// -------------------------------------- k_pvs: Pacc[z] = P @ E (split-K x8)
// 128x128 tile, K span 1280 (20 x BK=64). 32x4x8 = 1024 blocks (4/CU).
__global__ __launch_bounds__(256, 4) void k_pvs(const u16* __restrict__ Pg,
                                                const u16* __restrict__ ETb,
                                                float* __restrict__ Pacc) {
  __shared__ u16 S[16384];
  u16* As = S;
  u16* Bs = S + 8192;
  int tid = threadIdx.x;
  int m0 = blockIdx.x * 128;
  int d0 = blockIdx.y * 128;
  int z = blockIdx.z;
  int w = tid >> 6, l = tid & 63;
  int l15 = l & 15, quad = l >> 4;
  int mhalf = w >> 1, nhalf = w & 1;
  int lr = l >> 3, lg = l & 7;
  f32x4 acc[4][4] = {};
  int kt0 = z * 20;

  for (int kt = kt0; kt < kt0 + 20; ++kt) {
    #pragma unroll
    for (int i = 0; i < 4; ++i) {
      int wc = i * 4 + w;
      int row = wc * 8 + lr;
      int g = lg ^ (row & 7);
      GLDS(Pg + (size_t)(m0 + row) * VPAD + kt * 64 + g * 8, As + wc * 512);
      GLDS(ETb + (size_t)(d0 + row) * VPAD + kt * 64 + g * 8, Bs + wc * 512);
    }
    __syncthreads();
    #pragma unroll
    for (int kk = 0; kk < 2; ++kk) {
      bf16x8 a[4], b[4];
      #pragma unroll
      for (int mi = 0; mi < 4; ++mi) {
        int arow = mhalf * 64 + mi * 16 + l15;
        int slot = (kk * 4 + quad) ^ (arow & 7);
        a[mi] = *(const bf16x8*)&As[arow * 64 + slot * 8];
      }
      #pragma unroll
      for (int ni = 0; ni < 4; ++ni) {
        int brow = nhalf * 64 + ni * 16 + l15;
        int slot = (kk * 4 + quad) ^ (brow & 7);
        b[ni] = *(const bf16x8*)&Bs[brow * 64 + slot * 8];
      }
      #pragma unroll
      for (int mi = 0; mi < 4; ++mi)
        #pragma unroll
        for (int ni = 0; ni < 4; ++ni)
          acc[mi][ni] = __builtin_amdgcn_mfma_f32_16x16x32_bf16(a[mi], b[ni], acc[mi][ni], 0, 0, 0);
    }
    __syncthreads();
  }
  float* dst = Pacc + (size_t)z * (MM * DD);
  #pragma unroll
  for (int mi = 0; mi < 4; ++mi)
    #pragma unroll
    for (int ni = 0; ni < 4; ++ni)
      #pragma unroll
      for (int r = 0; r < 4; ++r) {
        int m = m0 + mhalf * 64 + mi * 16 + quad * 4 + r;
        int d = d0 + nhalf * 64 + ni * 16 + l15;
        dst[(size_t)m * DD + d] = acc[mi][ni][r];
      }
}

// -------------------------------------- k3 (FALLBACK): Out += P @ E (RMW f32)
__global__ __launch_bounds__(256) void k_pv(const u16* __restrict__ Pg,
                                            const u16* __restrict__ ETb,
                                            float* __restrict__ Out,
                                            int cbase, int W) {
  __shared__ u16 As[128 * 64];
  __shared__ u16 Bs[64 * 64];
  int tid = threadIdx.x;
  int m0 = blockIdx.x * 128;
  int n0 = blockIdx.y * 64;
  int w = tid >> 6, l = tid & 63;
  int l15 = l & 15, quad = l >> 4;
  int lr = l >> 3, lg = l & 7;
  int iters = W >> 6;
  f32x4 acc[2][4] = {};

  for (int kt = 0; kt < iters; ++kt) {
    #pragma unroll
    for (int i = 0; i < 4; ++i) {
      int wc = i * 4 + w;
      int row = wc * 8 + lr;
      int g = lg ^ (row & 7);
      GLDS(Pg + (size_t)(m0 + row) * W + kt * 64 + g * 8, As + wc * 512);
      if (i < 2)
        GLDS(ETb + (size_t)(n0 + row) * VPAD + cbase + kt * 64 + g * 8, Bs + wc * 512);
    }
    __syncthreads();
    #pragma unroll
    for (int kk = 0; kk < 2; ++kk) {
      bf16x8 a[2], b[4];
      #pragma unroll
      for (int mi = 0; mi < 2; ++mi) {
        int arow = w * 32 + mi * 16 + l15;
        int slot = (kk * 4 + quad) ^ (arow & 7);
        a[mi] = *(const bf16x8*)&As[arow * 64 + slot * 8];
      }
      #pragma unroll
      for (int ni = 0; ni < 4; ++ni) {
        int brow = ni * 16 + l15;
        int slot = (kk * 4 + quad) ^ (brow & 7);
        b[ni] = *(const bf16x8*)&Bs[brow * 64 + slot * 8];
      }
      #pragma unroll
      for (int mi = 0; mi < 2; ++mi)
        #pragma unroll
        for (int ni = 0; ni < 4; ++ni)
          acc[mi][ni] = __builtin_amdgcn_mfma_f32_16x16x32_bf16(a[mi], b[ni], acc[mi][ni], 0, 0, 0);
    }
    __syncthreads();
  }
  #pragma unroll
  for (int mi = 0; mi < 2; ++mi)
    #pragma unroll
    for (int ni = 0; ni < 4; ++ni)
      #pragma unroll
      for (int r = 0; r < 4; ++r) {
        int m = m0 + w * 32 + mi * 16 + quad * 4 + r;
        int d = n0 + ni * 16 + l15;
        Out[(size_t)m * DD + d] += acc[mi][ni][r];
      }
}

// ------------------------------------------- k_fin8: out = sum(Pacc)/l + q
__global__ __launch_bounds__(256) void k_fin8(float* __restrict__ Out,
                                              const float* __restrict__ Lacc,
                                              const u16* __restrict__ Qb,
                                              const float* __restrict__ Pacc) {
  int idx = blockIdx.x * 256 + threadIdx.x;
  int m = idx >> 7;
  int d4 = (idx & 127) * 4;
  float inv = 1.f / Lacc[m];
  size_t off = (size_t)m * DD + d4;
  f32x4 s = {0.f, 0.f, 0.f, 0.f};
  #pragma unroll
  for (int z = 0; z < 8; ++z)
    s += *(const f32x4*)(Pacc + (size_t)z * (MM * DD) + off);
  const u16* qp = Qb + off;
  f32x4 r;
  #pragma unroll
  for (int i = 0; i < 4; ++i) r[i] = s[i] * inv + bf2f(qp[i]);
  *(f32x4*)(Out + off) = r;
}

// ------------------------------------------- k4 (FALLBACK): out = out/l + q
__global__ __launch_bounds__(256) void k_fin(float* __restrict__ Out,
                                             const float* __restrict__ Lacc,
                                             const u16* __restrict__ Qb) {
  int idx = blockIdx.x * 256 + threadIdx.x;
  int m = idx >> 7;
  int d4 = (idx & 127) * 4;
  float inv = 1.f / Lacc[m];
  f32x4 ov = *(const f32x4*)(Out + (size_t)m * DD + d4);
  const u16* qp = Qb + (size_t)m * DD + d4;
  f32x4 r;
  #pragma unroll
  for (int i = 0; i < 4; ++i) r[i] = ov[i] * inv + bf2f(qp[i]);
  *(f32x4*)(Out + (size_t)m * DD + d4) = r;
}

extern "C" void kernel_launch(void* const* d_in, const int* in_sizes, int n_in,
                              void* d_out, int out_size, void* d_ws, size_t ws_size,
                              hipStream_t stream) {
  const float* x  = (const float*)d_in[0];
  const float* Wp = (const float*)d_in[1];
  const float* E  = (const float*)d_in[2];
  float* out = (float*)d_out;
  char* ws = (char*)d_ws;
  u16*   Qb   = (u16*)(ws + WS_Q);
  u16*   Eb   = (u16*)(ws + WS_EB);
  u16*   ETb  = (u16*)(ws + WS_ET);
  float* Lacc = (float*)(ws + WS_LACC);
  u16*   Pc   = (u16*)(ws + WS_P);
  u16*   Xb   = (u16*)(ws + WS_P + OFF_XB);
  u16*   Wb   = (u16*)(ws + WS_P + OFF_WB);
  float* Qacc = (float*)(ws + WS_P + OFF_QA);
  float* Pacc = (float*)(ws + WS_PACC);

  bool fastg = ws_size >= (size_t)FAST_NEED;
  bool fullp = ws_size >= (size_t)FULLP_NEED;

  k_eprep<<<dim3(VPAD / 64, DD / 64), 256, 0, stream>>>(E, Eb, ETb, out, Lacc);
  if (fastg) {
    k_conv<<<dim3(MM + DD), 256, 0, stream>>>(x, Wp, Xb, Wb);
    k_g1<<<dim3(MM / 128, DD / 64, 2), 256, 0, stream>>>(Xb, Wb, Qacc);
    k_tanh<<<dim3(MM * DD / 8 / 256), 256, 0, stream>>>(Qacc, Qb);
  } else {
    k_gemm1<<<dim3(MM / 64, DD / 64), 256, 0, stream>>>(x, Wp, Qb);
  }
  if (fullp) {
    k_s  <<<dim3(MM / 128, VPAD / 128), 256, 0, stream>>>(Qb, Eb, Pc, Lacc, 0, VPAD);
    k_pvs<<<dim3(MM / 128, DD / 128, 8), 256, 0, stream>>>(Pc, ETb, Pacc);
    k_fin8<<<dim3(MM * DD / 4 / 256), 256, 0, stream>>>(out, Lacc, Qb, Pacc);
  } else {
    int W = 640;
    if (ws_size >= (size_t)WS_P + (size_t)MM * 2560 * 2) W = 2560;
    else if (ws_size >= (size_t)WS_P + (size_t)MM * 1280 * 2) W = 1280;
    int nch = VPAD / W;
    for (int c = 0; c < nch; ++c) {
      k_s <<<dim3(MM / 128, W / 128), 256, 0, stream>>>(Qb, Eb, Pc, Lacc, c * W, W);
      k_pv<<<dim3(MM / 128, DD / 64), 256, 0, stream>>>(Pc, ETb, out, c * W, W);
    }
    k_fin<<<dim3(MM * DD / 4 / 256), 256, 0, stream>>>(out, Lacc, Qb);
  }
}

// Round 5
// 272.829 us; speedup vs baseline: 1.7256x; 1.0915x over previous
//
#include <hip/hip_runtime.h>
#include <hip/hip_bf16.h>

typedef unsigned short u16;
typedef unsigned int u32;
typedef unsigned char u8;
typedef __bf16 bf16x8 __attribute__((ext_vector_type(8)));
typedef u16 u16x8 __attribute__((ext_vector_type(8)));
typedef float f32x4 __attribute__((ext_vector_type(4)));
typedef u32 u32x4 __attribute__((ext_vector_type(4)));

#define MM   4096      // B*L
#define CC   4000      // char vocab (K of gemm1)
#define KP   4096      // padded K for gemm1 fast path
#define DD   512       // d_vec
#define VV   10000     // emb rows
#define VPAD 10240     // 80*128, zero-padded tail

// ---------------- fp8 fast-path ws layout (bytes) ----------------
#define WS8_QB   0u          // Qb  bf16 [4096][512]   = 4,194,304
#define WS8_QF   4194304u    // Qf  fp8  [4096][512]   = 2,097,152  (q*4)
#define WS8_EF   6291456u    // Ef  fp8  [10240][512]  = 5,242,880  (E*16)
#define WS8_ETF  11534336u   // ETf fp8  [512][10240]  = 5,242,880  (E*16)
#define WS8_LACC 16777216u   // Lacc f32 [4096]
#define WS8_R    16793600u   // region: Xb/Wb/Qacc (gemm1 phase) then Pf (attn)
#define R_XB     0u          //   Xb bf16 [4096][4096] = 33,554,432
#define R_WB     33554432u   //   Wb bf16 [512][4096]  =  4,194,304
#define R_QA     37748736u   //   Qacc f32 [4][4096][512] = 33,554,432
                             //   Pf fp8 [4096][10240] = 41,943,040 (aliases Xb/Wb/QA)
#define WS8_PACC 88096768u   // Pacc f32 [4][4096][512] = 33,554,432
#define FAST8_NEED 121651200u

// ---------------- bf16 fallback ws layout (round-2 style) ----------------
#define WS_Q    0u
#define WS_EB   4194304u
#define WS_ET   14680064u
#define WS_LACC 25165824u
#define WS_P    25182208u

__device__ __forceinline__ u16 f2bf(float f) {
  u32 u = __builtin_bit_cast(u32, f);
  return (u16)((u + 0x7FFFu + ((u >> 16) & 1u)) >> 16);  // RNE
}
__device__ __forceinline__ float bf2f(u16 h) {
  u32 u = (u32)h << 16;
  return __builtin_bit_cast(float, u);
}
// f32 -> e4m3fn (OCP), RNE, flush below 2^-6 to 0, no sat (inputs bounded <448)
__device__ __forceinline__ u8 f2fp8(float f) {
  u32 u = __builtin_bit_cast(u32, f);
  u32 s = (u >> 31) << 7;
  u32 m = u & 0x7FFFFFFFu;
  if (m < 0x3C800000u) return (u8)s;              // < 2^-6 -> +/-0
  u32 r = m + 0x7FFFFu + ((m >> 20) & 1u);        // RNE at bit 20
  return (u8)(((r >> 20) - 960u) | s);
}

// async global->LDS, 16B per lane; LDS dest is wave-uniform base + lane*16
#define GLDS(gp, lp) __builtin_amdgcn_global_load_lds( \
    (const __attribute__((address_space(1))) void*)(gp), \
    (__attribute__((address_space(3))) void*)(lp), 16, 0, 0)

// fp8 LDS frag addressing: rows of 64B, 8 octets, chunk(16B)-XOR swizzle
__device__ __forceinline__ int fo8(int row, int o) {
  return row * 64 + ((((o >> 1) ^ ((row >> 1) & 3)) << 4) | ((o & 1) << 3));
}

// =============================== fp8 fast path ===============================

// k_eprep8: E -> Ef (x16 fp8) + ETf (x16 fp8, transposed), zero-pad v>=VV,
// zero Lacc. Grid (VPAD/64, DD/64).
__global__ __launch_bounds__(256) void k_eprep8(const float* __restrict__ E,
                                                u8* __restrict__ Ef,
                                                u8* __restrict__ ETf,
                                                float* __restrict__ Lacc) {
  __shared__ u8 st[64 * 68];
  int tid = threadIdx.x;
  {
    int flat = blockIdx.x * 8 + blockIdx.y;
    int fid = flat * 256 + tid;
    if (fid < MM) Lacc[fid] = 0.f;
  }
  int v0 = blockIdx.x * 64, d0 = blockIdx.y * 64;
  int r = tid >> 2, seg = tid & 3;
  u8 h[16];
  int v = v0 + r;
  if (v < VV) {
    const float* src = E + (size_t)v * DD + d0 + seg * 16;
    #pragma unroll
    for (int j = 0; j < 4; ++j) {
      float4 t = *(const float4*)(src + j * 4);
      h[4*j+0] = f2fp8(t.x * 16.f); h[4*j+1] = f2fp8(t.y * 16.f);
      h[4*j+2] = f2fp8(t.z * 16.f); h[4*j+3] = f2fp8(t.w * 16.f);
    }
  } else {
    #pragma unroll
    for (int j = 0; j < 16; ++j) h[j] = 0;
  }
  { // Ef row-major (coalesced 16B)
    u32x4 p;
    #pragma unroll
    for (int q = 0; q < 4; ++q)
      p[q] = (u32)h[4*q] | ((u32)h[4*q+1] << 8) | ((u32)h[4*q+2] << 16) | ((u32)h[4*q+3] << 24);
    *(u32x4*)(Ef + (size_t)v * DD + d0 + seg * 16) = p;
  }
  #pragma unroll
  for (int j = 0; j < 16; ++j) st[r * 68 + seg * 16 + j] = h[j];
  __syncthreads();
  { // ETf: thread owns d-row d0+r, v-seg seg*16 (coalesced 16B)
    u8 g[16];
    #pragma unroll
    for (int j = 0; j < 16; ++j) g[j] = st[(seg * 16 + j) * 68 + r];
    u32x4 p;
    #pragma unroll
    for (int q = 0; q < 4; ++q)
      p[q] = (u32)g[4*q] | ((u32)g[4*q+1] << 8) | ((u32)g[4*q+2] << 16) | ((u32)g[4*q+3] << 24);
    *(u32x4*)(ETf + (size_t)(d0 + r) * VPAD + v0 + seg * 16) = p;
  }
}

// k_conv: X,W f32 -> bf16, K padded 4000->4096
__global__ __launch_bounds__(256) void k_conv(const float* __restrict__ X,
                                              const float* __restrict__ Wp,
                                              u16* __restrict__ Xb,
                                              u16* __restrict__ Wb) {
  int row = blockIdx.x;
  int t = threadIdx.x;
  const float* src;
  u16* dst;
  if (row < MM) { src = X + (size_t)row * CC; dst = Xb + (size_t)row * KP; }
  else { src = Wp + (size_t)(row - MM) * CC; dst = Wb + (size_t)(row - MM) * KP; }
  int c0 = t * 16;
  u16 h[16];
  if (c0 + 16 <= CC) {
    #pragma unroll
    for (int j = 0; j < 4; ++j) {
      float4 v = *(const float4*)(src + c0 + j * 4);
      h[4*j+0] = f2bf(v.x); h[4*j+1] = f2bf(v.y); h[4*j+2] = f2bf(v.z); h[4*j+3] = f2bf(v.w);
    }
  } else {
    #pragma unroll
    for (int j = 0; j < 16; ++j) h[j] = 0;
  }
  u16x8 p0, p1;
  #pragma unroll
  for (int j = 0; j < 8; ++j) { p0[j] = h[j]; p1[j] = h[8+j]; }
  *(u16x8*)(dst + c0) = p0; *(u16x8*)(dst + c0 + 8) = p1;
}

// k_g1: Qacc[z] = Xb @ Wb^T, split-K x4 (1024 blocks)
__global__ __launch_bounds__(256) void k_g1(const u16* __restrict__ Xb,
                                            const u16* __restrict__ Wb,
                                            float* __restrict__ Qacc) {
  __shared__ u16 As[128 * 64];
  __shared__ u16 Bs[64 * 64];
  int tid = threadIdx.x;
  int m0 = blockIdx.x * 128;
  int n0 = blockIdx.y * 64;
  int kt0 = blockIdx.z * 16;
  int w = tid >> 6, l = tid & 63;
  int l15 = l & 15, quad = l >> 4;
  int lr = l >> 3, lg = l & 7;
  f32x4 acc[2][4] = {};

  for (int kt = kt0; kt < kt0 + 16; ++kt) {
    #pragma unroll
    for (int i = 0; i < 4; ++i) {
      int wc = i * 4 + w;
      int row = wc * 8 + lr;
      int g = lg ^ (row & 7);
      GLDS(Xb + (size_t)(m0 + row) * KP + kt * 64 + g * 8, As + wc * 512);
      if (i < 2)
        GLDS(Wb + (size_t)(n0 + row) * KP + kt * 64 + g * 8, Bs + wc * 512);
    }
    __syncthreads();
    #pragma unroll
    for (int kk = 0; kk < 2; ++kk) {
      bf16x8 a[2], b[4];
      #pragma unroll
      for (int mi = 0; mi < 2; ++mi) {
        int arow = w * 32 + mi * 16 + l15;
        int slot = (kk * 4 + quad) ^ (arow & 7);
        a[mi] = *(const bf16x8*)&As[arow * 64 + slot * 8];
      }
      #pragma unroll
      for (int ni = 0; ni < 4; ++ni) {
        int brow = ni * 16 + l15;
        int slot = (kk * 4 + quad) ^ (brow & 7);
        b[ni] = *(const bf16x8*)&Bs[brow * 64 + slot * 8];
      }
      #pragma unroll
      for (int mi = 0; mi < 2; ++mi)
        #pragma unroll
        for (int ni = 0; ni < 4; ++ni)
          acc[mi][ni] = __builtin_amdgcn_mfma_f32_16x16x32_bf16(a[mi], b[ni], acc[mi][ni], 0, 0, 0);
    }
    __syncthreads();
  }
  float* dst = Qacc + (size_t)blockIdx.z * (MM * DD);
  #pragma unroll
  for (int mi = 0; mi < 2; ++mi)
    #pragma unroll
    for (int ni = 0; ni < 4; ++ni)
      #pragma unroll
      for (int r = 0; r < 4; ++r) {
        int m = m0 + w * 32 + mi * 16 + quad * 4 + r;
        int d = n0 + ni * 16 + l15;
        dst[(size_t)m * DD + d] = acc[mi][ni][r];
      }
}

// k_tanh4: q = tanh(sum of 4 partials); Qb bf16 + Qf fp8 (q*4)
__global__ __launch_bounds__(256) void k_tanh4(const float* __restrict__ Qacc,
                                               u16* __restrict__ Qb,
                                               u8* __restrict__ Qf) {
  int idx = blockIdx.x * 256 + threadIdx.x;
  size_t base = (size_t)idx * 8;
  f32x4 s0 = {0,0,0,0}, s1 = {0,0,0,0};
  #pragma unroll
  for (int z = 0; z < 4; ++z) {
    s0 += *(const f32x4*)(Qacc + (size_t)z * (MM * DD) + base);
    s1 += *(const f32x4*)(Qacc + (size_t)z * (MM * DD) + base + 4);
  }
  float t[8];
  #pragma unroll
  for (int j = 0; j < 4; ++j) t[j] = tanhf(s0[j]);
  #pragma unroll
  for (int j = 0; j < 4; ++j) t[4+j] = tanhf(s1[j]);
  u16x8 p;
  #pragma unroll
  for (int j = 0; j < 8; ++j) p[j] = f2bf(t[j]);
  *(u16x8*)(Qb + base) = p;
  unsigned long long q8 = 0;
  #pragma unroll
  for (int j = 0; j < 8; ++j) q8 |= ((unsigned long long)f2fp8(t[j] * 4.f)) << (8 * j);
  *(unsigned long long*)(Qf + base) = q8;
}

// k_s8: P = exp((Qf.Ef^T)/64), fp8. 128x128 tile, BK=64, fp8 MFMA.
// l += exact-f32 rowsum. Pf = fp8(P/4), coalesced via swizzled LDS.
__global__ __launch_bounds__(256, 4) void k_s8(const u8* __restrict__ Qf,
                                               const u8* __restrict__ Ef,
                                               u8* __restrict__ Pf,
                                               float* __restrict__ Lacc) {
  __shared__ u8 S8[16384];       // As 8K | Bs 8K; epilogue: P-tile 16K
  u8* As = S8;
  u8* Bs = S8 + 8192;
  int tid = threadIdx.x;
  int m0 = blockIdx.x * 128;
  int n0 = blockIdx.y * 128;
  int w = tid >> 6, l = tid & 63;
  int l15 = l & 15, quad = l >> 4;
  int mhalf = w >> 1, nhalf = w & 1;
  int srow = tid >> 2, schunk = tid & 3;           // staging: 64 rows x 4 chunks
  int sw0 = schunk ^ ((srow >> 1) & 3);
  int sw1 = schunk ^ (((srow + 64) >> 1) & 3);
  const u8* qa0 = Qf + (size_t)(m0 + srow) * DD + sw0 * 16;
  const u8* qa1 = Qf + (size_t)(m0 + 64 + srow) * DD + sw1 * 16;
  const u8* eb0 = Ef + (size_t)(n0 + srow) * DD + sw0 * 16;
  const u8* eb1 = Ef + (size_t)(n0 + 64 + srow) * DD + sw1 * 16;
  f32x4 acc[4][4] = {};

  for (int kt = 0; kt < 8; ++kt) {
    GLDS(qa0 + kt * 64, As + tid * 16);
    GLDS(qa1 + kt * 64, As + 4096 + tid * 16);
    GLDS(eb0 + kt * 64, Bs + tid * 16);
    GLDS(eb1 + kt * 64, Bs + 4096 + tid * 16);
    __syncthreads();
    #pragma unroll
    for (int kk = 0; kk < 2; ++kk) {
      long a[4], b[4];
      #pragma unroll
      for (int mi = 0; mi < 4; ++mi) {
        int arow = mhalf * 64 + mi * 16 + l15;
        a[mi] = *(const long*)&As[fo8(arow, kk * 4 + quad)];
      }
      #pragma unroll
      for (int ni = 0; ni < 4; ++ni) {
        int brow = nhalf * 64 + ni * 16 + l15;
        b[ni] = *(const long*)&Bs[fo8(brow, kk * 4 + quad)];
      }
      #pragma unroll
      for (int mi = 0; mi < 4; ++mi)
        #pragma unroll
        for (int ni = 0; ni < 4; ++ni)
          acc[mi][ni] = __builtin_amdgcn_mfma_f32_16x16x32_fp8_fp8(a[mi], b[ni], acc[mi][ni], 0, 0, 0);
    }
    __syncthreads();
  }

  // epilogue: p = exp(s/64) (exact f32 rowsum -> Lacc); Pf = fp8(p/4)
  float rs[4][4] = {};
  #pragma unroll
  for (int mi = 0; mi < 4; ++mi) {
    #pragma unroll
    for (int ni = 0; ni < 4; ++ni) {
      int colL = nhalf * 64 + ni * 16 + l15;
      bool ok = (n0 + colL) < VV;
      #pragma unroll
      for (int r = 0; r < 4; ++r) {
        int rowL = mhalf * 64 + mi * 16 + quad * 4 + r;
        float p = ok ? __expf(fminf(acc[mi][ni][r] * 0.015625f, 5.9f)) : 0.f;
        rs[mi][r] += p;
        S8[rowL * 128 + (((colL >> 4) ^ (rowL & 7)) << 4) + (colL & 15)] = f2fp8(p * 0.25f);
      }
    }
  }
  __syncthreads();
  { // coalesced Pf store: row = tid>>1, 64B half = tid&1
    int row = tid >> 1, h2 = tid & 1;
    size_t gbase = (size_t)(m0 + row) * VPAD + n0 + h2 * 64;
    #pragma unroll
    for (int c = 0; c < 4; ++c) {
      int slot = (h2 * 4 + c) ^ (row & 7);
      *(u32x4*)(Pf + gbase + c * 16) = *(const u32x4*)&S8[row * 128 + slot * 16];
    }
  }
  #pragma unroll
  for (int mi = 0; mi < 4; ++mi)
    #pragma unroll
    for (int r = 0; r < 4; ++r) {
      float v = rs[mi][r];
      v += __shfl_xor(v, 1, 16);
      v += __shfl_xor(v, 2, 16);
      v += __shfl_xor(v, 4, 16);
      v += __shfl_xor(v, 8, 16);
      if (l15 == 0)
        atomicAdd(&Lacc[m0 + mhalf * 64 + mi * 16 + quad * 4 + r], v);
    }
}

// k_pvs8: Pacc[z] = Pf @ ETf^T-slice, fp8, split-K x4 (40-iter K loops)
__global__ __launch_bounds__(256, 4) void k_pvs8(const u8* __restrict__ Pf,
                                                 const u8* __restrict__ ETf,
                                                 float* __restrict__ Pacc) {
  __shared__ u8 S8[16384];
  u8* As = S8;
  u8* Bs = S8 + 8192;
  int tid = threadIdx.x;
  int m0 = blockIdx.x * 128;
  int d0 = blockIdx.y * 128;
  int z = blockIdx.z;
  int w = tid >> 6, l = tid & 63;
  int l15 = l & 15, quad = l >> 4;
  int mhalf = w >> 1, nhalf = w & 1;
  int srow = tid >> 2, schunk = tid & 3;
  int sw0 = schunk ^ ((srow >> 1) & 3);
  int sw1 = schunk ^ (((srow + 64) >> 1) & 3);
  const u8* pa0 = Pf + (size_t)(m0 + srow) * VPAD + sw0 * 16;
  const u8* pa1 = Pf + (size_t)(m0 + 64 + srow) * VPAD + sw1 * 16;
  const u8* eb0 = ETf + (size_t)(d0 + srow) * VPAD + sw0 * 16;
  const u8* eb1 = ETf + (size_t)(d0 + 64 + srow) * VPAD + sw1 * 16;
  f32x4 acc[4][4] = {};
  int kt0 = z * 40;

  for (int kt = kt0; kt < kt0 + 40; ++kt) {
    GLDS(pa0 + kt * 64, As + tid * 16);
    GLDS(pa1 + kt * 64, As + 4096 + tid * 16);
    GLDS(eb0 + kt * 64, Bs + tid * 16);
    GLDS(eb1 + kt * 64, Bs + 4096 + tid * 16);
    __syncthreads();
    #pragma unroll
    for (int kk = 0; kk < 2; ++kk) {
      long a[4], b[4];
      #pragma unroll
      for (int mi = 0; mi < 4; ++mi) {
        int arow = mhalf * 64 + mi * 16 + l15;
        a[mi] = *(const long*)&As[fo8(arow, kk * 4 + quad)];
      }
      #pragma unroll
      for (int ni = 0; ni < 4; ++ni) {
        int brow = nhalf * 64 + ni * 16 + l15;
        b[ni] = *(const long*)&Bs[fo8(brow, kk * 4 + quad)];
      }
      #pragma unroll
      for (int mi = 0; mi < 4; ++mi)
        #pragma unroll
        for (int ni = 0; ni < 4; ++ni)
          acc[mi][ni] = __builtin_amdgcn_mfma_f32_16x16x32_fp8_fp8(a[mi], b[ni], acc[mi][ni], 0, 0, 0);
    }
    __syncthreads();
  }
  float* dst = Pacc + (size_t)z * (MM * DD);
  #pragma unroll
  for (int mi = 0; mi < 4; ++mi)
    #pragma unroll
    for (int ni = 0; ni < 4; ++ni)
      #pragma unroll
      for (int r = 0; r < 4; ++r) {
        int m = m0 + mhalf * 64 + mi * 16 + quad * 4 + r;
        int d = d0 + nhalf * 64 + ni * 16 + l15;
        dst[(size_t)m * DD + d] = acc[mi][ni][r];
      }
}

// k_fin4: out = (sum of 4 Pacc) * 0.25/l + q   (scales: Pf=p/4, ETf=16E)
__global__ __launch_bounds__(256) void k_fin4(float* __restrict__ Out,
                                              const float* __restrict__ Lacc,
                                              const u16* __restrict__ Qb,
                                              const float* __restrict__ Pacc) {
  int idx = blockIdx.x * 256 + threadIdx.x;
  int m = idx >> 7;
  int d4 = (idx & 127) * 4;
  float inv = 0.25f / Lacc[m];
  size_t off = (size_t)m * DD + d4;
  f32x4 s = {0.f, 0.f, 0.f, 0.f};
  #pragma unroll
  for (int z = 0; z < 4; ++z)
    s += *(const f32x4*)(Pacc + (size_t)z * (MM * DD) + off);
  const u16* qp = Qb + off;
  f32x4 r;
  #pragma unroll
  for (int i = 0; i < 4; ++i) r[i] = s[i] * inv + bf2f(qp[i]);
  *(f32x4*)(Out + off) = r;
}

// =============================== bf16 fallback ===============================

__global__ __launch_bounds__(256) void k_eprep(const float* __restrict__ E,
                                               u16* __restrict__ Eb,
                                               u16* __restrict__ ETb,
                                               float* __restrict__ Out,
                                               float* __restrict__ Lacc) {
  __shared__ u16 st[64 * 65];
  int tid = threadIdx.x;
  {
    int bid = blockIdx.x * 8 + blockIdx.y;
    f32x4 z = {0.f, 0.f, 0.f, 0.f};
    #pragma unroll
    for (int rep = 0; rep < 2; ++rep) {
      int id = bid * 256 + tid + rep * 327680;
      if (id < 524288)      *(f32x4*)(Out + (size_t)id * 4) = z;
      else if (id < 525312) *(f32x4*)(Lacc + (size_t)(id - 524288) * 4) = z;
    }
  }
  int v0 = blockIdx.x * 64, d0 = blockIdx.y * 64;
  int r = tid >> 2, seg = tid & 3;
  u16 h[16];
  int v = v0 + r;
  if (v < VV) {
    const float* src = E + (size_t)v * DD + d0 + seg * 16;
    #pragma unroll
    for (int j = 0; j < 4; ++j) {
      float4 t = *(const float4*)(src + j * 4);
      h[4*j+0] = f2bf(t.x); h[4*j+1] = f2bf(t.y); h[4*j+2] = f2bf(t.z); h[4*j+3] = f2bf(t.w);
    }
  } else {
    #pragma unroll
    for (int j = 0; j < 16; ++j) h[j] = 0;
  }
  {
    u16x8 p0, p1;
    #pragma unroll
    for (int j = 0; j < 8; ++j) { p0[j] = h[j]; p1[j] = h[8+j]; }
    u16* dst = Eb + (size_t)v * DD + d0 + seg * 16;
    *(u16x8*)dst = p0; *(u16x8*)(dst + 8) = p1;
  }
  #pragma unroll
  for (int j = 0; j < 16; ++j) st[r * 65 + seg * 16 + j] = h[j];
  __syncthreads();
  {
    u16 g[16];
    #pragma unroll
    for (int j = 0; j < 16; ++j) g[j] = st[(seg * 16 + j) * 65 + r];
    u16x8 p0, p1;
    #pragma unroll
    for (int j = 0; j < 8; ++j) { p0[j] = g[j]; p1[j] = g[8+j]; }
    u16* dst = ETb + (size_t)(d0 + r) * VPAD + v0 + seg * 16;
    *(u16x8*)dst = p0; *(u16x8*)(dst + 8) = p1;
  }
}

__global__ __launch_bounds__(256) void k_gemm1(const float* __restrict__ X,
                                               const float* __restrict__ W,
                                               u16* __restrict__ Qb) {
  __shared__ u16 xs[64 * 64];
  __shared__ u16 wst[64 * 64];
  int tid = threadIdx.x;
  int m0 = blockIdx.x * 64;
  int n0 = blockIdx.y * 64;
  int srow = tid >> 2;
  int sseg = tid & 3;
  int r7 = srow & 7;
  const float* xsrc = X + (size_t)(m0 + srow) * CC + sseg * 16;
  const float* wsrc = W + (size_t)(n0 + srow) * CC + sseg * 16;
  int lane = tid & 63;
  int wv = tid >> 6;
  int l15 = lane & 15, quad = lane >> 4;
  f32x4 acc[4] = {};

  for (int kt = 0; kt < 63; ++kt) {
    int cbase = kt * 64 + sseg * 16;
    float xv[16], wf[16];
    if (cbase + 16 <= CC) {
      #pragma unroll
      for (int j = 0; j < 4; ++j) {
        float4 tx = *(const float4*)(xsrc + kt * 64 + j * 4);
        float4 tw = *(const float4*)(wsrc + kt * 64 + j * 4);
        xv[4*j+0] = tx.x; xv[4*j+1] = tx.y; xv[4*j+2] = tx.z; xv[4*j+3] = tx.w;
        wf[4*j+0] = tw.x; wf[4*j+1] = tw.y; wf[4*j+2] = tw.z; wf[4*j+3] = tw.w;
      }
    } else {
      #pragma unroll
      for (int j = 0; j < 16; ++j) { xv[j] = 0.f; wf[j] = 0.f; }
    }
    __syncthreads();
    #pragma unroll
    for (int j = 0; j < 2; ++j) {
      int g = (sseg * 2 + j) ^ r7;
      u16x8 px, pw;
      #pragma unroll
      for (int e = 0; e < 8; ++e) { px[e] = f2bf(xv[8*j+e]); pw[e] = f2bf(wf[8*j+e]); }
      *(u16x8*)&xs[srow * 64 + (g << 3)] = px;
      *(u16x8*)&wst[srow * 64 + (g << 3)] = pw;
    }
    __syncthreads();
    #pragma unroll
    for (int kk = 0; kk < 2; ++kk) {
      int arow = 16 * wv + l15;
      int ga = (kk * 4 + quad) ^ (arow & 7);
      bf16x8 a = *(const bf16x8*)&xs[arow * 64 + (ga << 3)];
      #pragma unroll
      for (int nb = 0; nb < 4; ++nb) {
        int brow = 16 * nb + l15;
        int gb = (kk * 4 + quad) ^ (brow & 7);
        bf16x8 b = *(const bf16x8*)&wst[brow * 64 + (gb << 3)];
        acc[nb] = __builtin_amdgcn_mfma_f32_16x16x32_bf16(a, b, acc[nb], 0, 0, 0);
      }
    }
  }
  #pragma unroll
  for (int nb = 0; nb < 4; ++nb) {
    int d = n0 + 16 * nb + l15;
    #pragma unroll
    for (int r = 0; r < 4; ++r) {
      int m = m0 + 16 * wv + 4 * quad + r;
      Qb[(size_t)m * DD + d] = f2bf(tanhf(acc[nb][r]));
    }
  }
}

__global__ __launch_bounds__(256) void k_s(const u16* __restrict__ Qb,
                                           const u16* __restrict__ Eb,
                                           u16* __restrict__ Pg,
                                           float* __restrict__ Lacc,
                                           int cbase, int W) {
  __shared__ u16 As[128 * 64];
  __shared__ u16 Bs[128 * 64];
  int tid = threadIdx.x;
  int m0 = blockIdx.x * 128;
  int n0 = blockIdx.y * 128;
  int w = tid >> 6, l = tid & 63;
  int l15 = l & 15, quad = l >> 4;
  int mhalf = w >> 1, nhalf = w & 1;
  int lr = l >> 3, lg = l & 7;
  f32x4 acc[4][4] = {};

  for (int kt = 0; kt < 8; ++kt) {
    #pragma unroll
    for (int i = 0; i < 4; ++i) {
      int wc = i * 4 + w;
      int row = wc * 8 + lr;
      int g = lg ^ (row & 7);
      GLDS(Qb + (size_t)(m0 + row) * DD + kt * 64 + g * 8, As + wc * 512);
      GLDS(Eb + (size_t)(cbase + n0 + row) * DD + kt * 64 + g * 8, Bs + wc * 512);
    }
    __syncthreads();
    #pragma unroll
    for (int kk = 0; kk < 2; ++kk) {
      bf16x8 a[4], b[4];
      #pragma unroll
      for (int mi = 0; mi < 4; ++mi) {
        int arow = mhalf * 64 + mi * 16 + l15;
        int slot = (kk * 4 + quad) ^ (arow & 7);
        a[mi] = *(const bf16x8*)&As[arow * 64 + slot * 8];
      }
      #pragma unroll
      for (int ni = 0; ni < 4; ++ni) {
        int brow = nhalf * 64 + ni * 16 + l15;
        int slot = (kk * 4 + quad) ^ (brow & 7);
        b[ni] = *(const bf16x8*)&Bs[brow * 64 + slot * 8];
      }
      #pragma unroll
      for (int mi = 0; mi < 4; ++mi)
        #pragma unroll
        for (int ni = 0; ni < 4; ++ni)
          acc[mi][ni] = __builtin_amdgcn_mfma_f32_16x16x32_bf16(a[mi], b[ni], acc[mi][ni], 0, 0, 0);
    }
    __syncthreads();
  }

  float rs[4][4] = {};
  #pragma unroll
  for (int mi = 0; mi < 4; ++mi) {
    #pragma unroll
    for (int ni = 0; ni < 4; ++ni) {
      int ncol = n0 + nhalf * 64 + ni * 16 + l15;
      bool ok = (cbase + ncol) < VV;
      #pragma unroll
      for (int r = 0; r < 4; ++r) {
        float p = ok ? __expf(acc[mi][ni][r]) : 0.f;
        rs[mi][r] += p;
        int m = m0 + mhalf * 64 + mi * 16 + quad * 4 + r;
        Pg[(size_t)m * W + ncol] = f2bf(p);
      }
    }
  }
  #pragma unroll
  for (int mi = 0; mi < 4; ++mi)
    #pragma unroll
    for (int r = 0; r < 4; ++r) {
      float v = rs[mi][r];
      v += __shfl_xor(v, 1, 16);
      v += __shfl_xor(v, 2, 16);
      v += __shfl_xor(v, 4, 16);
      v += __shfl_xor(v, 8, 16);
      if (l15 == 0)
        atomicAdd(&Lacc[m0 + mhalf * 64 + mi * 16 + quad * 4 + r], v);
    }
}

__global__ __launch_bounds__(256) void k_pv(const u16* __restrict__ Pg,
                                            const u16* __restrict__ ETb,
                                            float* __restrict__ Out,
                                            int cbase, int W) {
  __shared__ u16 As[128 * 64];
  __shared__ u16 Bs[64 * 64];
  int tid = threadIdx.x;
  int m0 = blockIdx.x * 128;
  int n0 = blockIdx.y * 64;
  int w = tid >> 6, l = tid & 63;
  int l15 = l & 15, quad = l >> 4;
  int lr = l >> 3, lg = l & 7;
  int iters = W >> 6;
  f32x4 acc[2][4] = {};

  for (int kt = 0; kt < iters; ++kt) {
    #pragma unroll
    for (int i = 0; i < 4; ++i) {
      int wc = i * 4 + w;
      int row = wc * 8 + lr;
      int g = lg ^ (row & 7);
      GLDS(Pg + (size_t)(m0 + row) * W + kt * 64 + g * 8, As + wc * 512);
      if (i < 2)
        GLDS(ETb + (size_t)(n0 + row) * VPAD + cbase + kt * 64 + g * 8, Bs + wc * 512);
    }
    __syncthreads();
    #pragma unroll
    for (int kk = 0; kk < 2; ++kk) {
      bf16x8 a[2], b[4];
      #pragma unroll
      for (int mi = 0; mi < 2; ++mi) {
        int arow = w * 32 + mi * 16 + l15;
        int slot = (kk * 4 + quad) ^ (arow & 7);
        a[mi] = *(const bf16x8*)&As[arow * 64 + slot * 8];
      }
      #pragma unroll
      for (int ni = 0; ni < 4; ++ni) {
        int brow = ni * 16 + l15;
        int slot = (kk * 4 + quad) ^ (brow & 7);
        b[ni] = *(const bf16x8*)&Bs[brow * 64 + slot * 8];
      }
      #pragma unroll
      for (int mi = 0; mi < 2; ++mi)
        #pragma unroll
        for (int ni = 0; ni < 4; ++ni)
          acc[mi][ni] = __builtin_amdgcn_mfma_f32_16x16x32_bf16(a[mi], b[ni], acc[mi][ni], 0, 0, 0);
    }
    __syncthreads();
  }
  #pragma unroll
  for (int mi = 0; mi < 2; ++mi)
    #pragma unroll
    for (int ni = 0; ni < 4; ++ni)
      #pragma unroll
      for (int r = 0; r < 4; ++r) {
        int m = m0 + w * 32 + mi * 16 + quad * 4 + r;
        int d = n0 + ni * 16 + l15;
        Out[(size_t)m * DD + d] += acc[mi][ni][r];
      }
}

__global__ __launch_bounds__(256) void k_fin(float* __restrict__ Out,
                                             const float* __restrict__ Lacc,
                                             const u16* __restrict__ Qb) {
  int idx = blockIdx.x * 256 + threadIdx.x;
  int m = idx >> 7;
  int d4 = (idx & 127) * 4;
  float inv = 1.f / Lacc[m];
  f32x4 ov = *(const f32x4*)(Out + (size_t)m * DD + d4);
  const u16* qp = Qb + (size_t)m * DD + d4;
  f32x4 r;
  #pragma unroll
  for (int i = 0; i < 4; ++i) r[i] = ov[i] * inv + bf2f(qp[i]);
  *(f32x4*)(Out + (size_t)m * DD + d4) = r;
}

extern "C" void kernel_launch(void* const* d_in, const int* in_sizes, int n_in,
                              void* d_out, int out_size, void* d_ws, size_t ws_size,
                              hipStream_t stream) {
  const float* x  = (const float*)d_in[0];
  const float* Wp = (const float*)d_in[1];
  const float* E  = (const float*)d_in[2];
  float* out = (float*)d_out;
  char* ws = (char*)d_ws;

  if (ws_size >= (size_t)FAST8_NEED) {
    u16*   Qb   = (u16*)(ws + WS8_QB);
    u8*    Qf   = (u8*)(ws + WS8_QF);
    u8*    Ef   = (u8*)(ws + WS8_EF);
    u8*    ETf  = (u8*)(ws + WS8_ETF);
    float* Lacc = (float*)(ws + WS8_LACC);
    u16*   Xb   = (u16*)(ws + WS8_R + R_XB);
    u16*   Wb   = (u16*)(ws + WS8_R + R_WB);
    float* Qacc = (float*)(ws + WS8_R + R_QA);
    u8*    Pf   = (u8*)(ws + WS8_R);
    float* Pacc = (float*)(ws + WS8_PACC);

    k_eprep8<<<dim3(VPAD / 64, DD / 64), 256, 0, stream>>>(E, Ef, ETf, Lacc);
    k_conv<<<dim3(MM + DD), 256, 0, stream>>>(x, Wp, Xb, Wb);
    k_g1<<<dim3(MM / 128, DD / 64, 4), 256, 0, stream>>>(Xb, Wb, Qacc);
    k_tanh4<<<dim3(MM * DD / 8 / 256), 256, 0, stream>>>(Qacc, Qb, Qf);
    k_s8<<<dim3(MM / 128, VPAD / 128), 256, 0, stream>>>(Qf, Ef, Pf, Lacc);
    k_pvs8<<<dim3(MM / 128, DD / 128, 4), 256, 0, stream>>>(Pf, ETf, Pacc);
    k_fin4<<<dim3(MM * DD / 4 / 256), 256, 0, stream>>>(out, Lacc, Qb, Pacc);
  } else {
    u16*   Qb   = (u16*)(ws + WS_Q);
    u16*   Eb   = (u16*)(ws + WS_EB);
    u16*   ETb  = (u16*)(ws + WS_ET);
    float* Lacc = (float*)(ws + WS_LACC);
    u16*   Pc   = (u16*)(ws + WS_P);
    int W = 640;
    if (ws_size >= (size_t)WS_P + (size_t)MM * 2560 * 2) W = 2560;
    else if (ws_size >= (size_t)WS_P + (size_t)MM * 1280 * 2) W = 1280;
    int nch = VPAD / W;
    k_eprep<<<dim3(VPAD / 64, DD / 64), 256, 0, stream>>>(E, Eb, ETb, out, Lacc);
    k_gemm1<<<dim3(MM / 64, DD / 64), 256, 0, stream>>>(x, Wp, Qb);
    for (int c = 0; c < nch; ++c) {
      k_s <<<dim3(MM / 128, W / 128), 256, 0, stream>>>(Qb, Eb, Pc, Lacc, c * W, W);
      k_pv<<<dim3(MM / 128, DD / 64), 256, 0, stream>>>(Pc, ETb, out, c * W, W);
    }
    k_fin<<<dim3(MM * DD / 4 / 256), 256, 0, stream>>>(out, Lacc, Qb);
  }
}

// Round 6
// 256.921 us; speedup vs baseline: 1.8325x; 1.0619x over previous
//
#include <hip/hip_runtime.h>
#include <hip/hip_bf16.h>

typedef unsigned short u16;
typedef unsigned int u32;
typedef unsigned char u8;
typedef __bf16 bf16x8 __attribute__((ext_vector_type(8)));
typedef u16 u16x8 __attribute__((ext_vector_type(8)));
typedef float f32x4 __attribute__((ext_vector_type(4)));
typedef u32 u32x4 __attribute__((ext_vector_type(4)));
typedef u32 u32x2 __attribute__((ext_vector_type(2)));
typedef long longx2 __attribute__((ext_vector_type(2)));

#define MM   4096      // B*L
#define CC   4000      // char vocab (K of gemm1)
#define KP   4096      // padded K for gemm1 fast path
#define DD   512       // d_vec
#define VV   10000     // emb rows
#define VPAD 10240     // 80*128, zero-padded tail

// ---------------- fp8 fast-path ws layout (bytes) ----------------
// Fp8 tensors use FRAGMENT-PAIR order within every 64-byte k-block:
// byte k -> pos ((k&31)>>3)*16 + ((k>>5)<<3) + (k&7); 16-B chunk q holds
// quad q's kk0 frag (bytes 0-7) and kk1 frag (bytes 8-15).
#define WS8_QB   0u          // Qb  bf16 [4096][512]   = 4,194,304
#define WS8_QF   4194304u    // Qf  fp8  [4096][512]   = 2,097,152  (q*4)
#define WS8_EF   6291456u    // Ef  fp8  [10240][512]  = 5,242,880  (E*16)
#define WS8_ETF  11534336u   // ETf fp8  [512][10240]  = 5,242,880  (E*16)
#define WS8_LACC 16777216u   // Lacc f32 [4096]
#define WS8_R    16793600u   // region: Xb/Wb/Qacc (gemm1 phase) then Pf (attn)
#define R_XB     0u          //   Xb bf16 [4096][4096] = 33,554,432
#define R_WB     33554432u   //   Wb bf16 [512][4096]  =  4,194,304
#define R_QA     37748736u   //   Qacc f32 [4][4096][512] = 33,554,432
                             //   Pf fp8 [4096][10240] = 41,943,040 (aliases)
#define WS8_PACC 88096768u   // Pacc f32 [8][4096][512] = 67,108,864
#define FAST8_NEED 155205632u

// ---------------- bf16 fallback ws layout ----------------
#define WS_Q    0u
#define WS_EB   4194304u
#define WS_ET   14680064u
#define WS_LACC 25165824u
#define WS_P    25182208u

__device__ __forceinline__ u16 f2bf(float f) {
  u32 u = __builtin_bit_cast(u32, f);
  return (u16)((u + 0x7FFFu + ((u >> 16) & 1u)) >> 16);  // RNE
}
__device__ __forceinline__ float bf2f(u16 h) {
  u32 u = (u32)h << 16;
  return __builtin_bit_cast(float, u);
}
__device__ __forceinline__ u8 f2fp8(float f) {   // manual e4m3fn fallback
  u32 u = __builtin_bit_cast(u32, f);
  u32 s = (u >> 31) << 7;
  u32 m = u & 0x7FFFFFFFu;
  if (m < 0x3C800000u) return (u8)s;
  u32 r = m + 0x7FFFFu + ((m >> 20) & 1u);
  return (u8)(((r >> 20) - 960u) | s);
}
// 4 floats -> 4 packed e4m3 bytes (HW v_cvt_pk_fp8_f32 when available)
__device__ __forceinline__ u32 pk4fp8(float f0, float f1, float f2, float f3) {
#if __has_builtin(__builtin_amdgcn_cvt_pk_fp8_f32)
  int w = 0;
  w = __builtin_amdgcn_cvt_pk_fp8_f32(f0, f1, w, false);
  w = __builtin_amdgcn_cvt_pk_fp8_f32(f2, f3, w, true);
  return (u32)w;
#else
  return (u32)f2fp8(f0) | ((u32)f2fp8(f1) << 8) |
         ((u32)f2fp8(f2) << 16) | ((u32)f2fp8(f3) << 24);
#endif
}

// async global->LDS, 16B per lane
#define GLDS(gp, lp) __builtin_amdgcn_global_load_lds( \
    (const __attribute__((address_space(1))) void*)(gp), \
    (__attribute__((address_space(3))) void*)(lp), 16, 0, 0)

// fp8 frag-pair read addr: row's chunk for quad q, chunk-XOR swizzled.
// Covers all 32 banks evenly per wave (b128 structural floor, no conflicts).
__device__ __forceinline__ int fr16(int row, int q) {
  return row * 64 + (((q ^ ((row >> 1) & 3)) << 4));
}
// dest group for 8-byte k-group j (j = k>>3 within 64-block)
__device__ __forceinline__ int pgrp(int j) { return (j & 3) * 2 + (j >> 2); }

// =============================== fp8 fast path ===============================

// k_eprep8: E -> Ef (x16) + ETf (x16, transposed), frag-pair permuted rows.
__global__ __launch_bounds__(256) void k_eprep8(const float* __restrict__ E,
                                                u8* __restrict__ Ef,
                                                u8* __restrict__ ETf,
                                                float* __restrict__ Lacc) {
  __shared__ u8 st[64 * 68];
  int tid = threadIdx.x;
  {
    int flat = blockIdx.x * 8 + blockIdx.y;
    int fid = flat * 256 + tid;
    if (fid < MM) Lacc[fid] = 0.f;
  }
  int v0 = blockIdx.x * 64, d0 = blockIdx.y * 64;
  int r = tid >> 2, seg = tid & 3;
  u32 w[4];
  int v = v0 + r;
  if (v < VV) {
    const float* src = E + (size_t)v * DD + d0 + seg * 16;
    #pragma unroll
    for (int j = 0; j < 4; ++j) {
      float4 t = *(const float4*)(src + j * 4);
      w[j] = pk4fp8(t.x * 16.f, t.y * 16.f, t.z * 16.f, t.w * 16.f);
    }
  } else {
    #pragma unroll
    for (int j = 0; j < 4; ++j) w[j] = 0;
  }
  int g0 = pgrp(2 * seg), g1 = pgrp(2 * seg + 1);
  { // Ef row-major, permuted: two 8-B stores
    size_t rowb = (size_t)v * DD + d0;
    u32x2 a = {w[0], w[1]}, b = {w[2], w[3]};
    *(u32x2*)(Ef + rowb + g0 * 8) = a;
    *(u32x2*)(Ef + rowb + g1 * 8) = b;
  }
  #pragma unroll
  for (int j = 0; j < 4; ++j)
    *(u32*)&st[r * 68 + seg * 16 + j * 4] = w[j];
  __syncthreads();
  { // ETf: thread owns d-row d0+r, v-bytes v0+seg*16..+16 (transposed read)
    u8 g[16];
    #pragma unroll
    for (int j = 0; j < 16; ++j) g[j] = st[(seg * 16 + j) * 68 + r];
    u32 t[4];
    #pragma unroll
    for (int q = 0; q < 4; ++q)
      t[q] = (u32)g[4*q] | ((u32)g[4*q+1] << 8) | ((u32)g[4*q+2] << 16) | ((u32)g[4*q+3] << 24);
    size_t rowb = (size_t)(d0 + r) * VPAD + v0;
    u32x2 a = {t[0], t[1]}, b = {t[2], t[3]};
    *(u32x2*)(ETf + rowb + g0 * 8) = a;
    *(u32x2*)(ETf + rowb + g1 * 8) = b;
  }
}

// k_conv: X,W f32 -> bf16, K padded 4000->4096
__global__ __launch_bounds__(256) void k_conv(const float* __restrict__ X,
                                              const float* __restrict__ Wp,
                                              u16* __restrict__ Xb,
                                              u16* __restrict__ Wb) {
  int row = blockIdx.x;
  int t = threadIdx.x;
  const float* src;
  u16* dst;
  if (row < MM) { src = X + (size_t)row * CC; dst = Xb + (size_t)row * KP; }
  else { src = Wp + (size_t)(row - MM) * CC; dst = Wb + (size_t)(row - MM) * KP; }
  int c0 = t * 16;
  u16 h[16];
  if (c0 + 16 <= CC) {
    #pragma unroll
    for (int j = 0; j < 4; ++j) {
      float4 v = *(const float4*)(src + c0 + j * 4);
      h[4*j+0] = f2bf(v.x); h[4*j+1] = f2bf(v.y); h[4*j+2] = f2bf(v.z); h[4*j+3] = f2bf(v.w);
    }
  } else {
    #pragma unroll
    for (int j = 0; j < 16; ++j) h[j] = 0;
  }
  u16x8 p0, p1;
  #pragma unroll
  for (int j = 0; j < 8; ++j) { p0[j] = h[j]; p1[j] = h[8+j]; }
  *(u16x8*)(dst + c0) = p0; *(u16x8*)(dst + c0 + 8) = p1;
}

// k_g1: Qacc[z] = Xb @ Wb^T, split-K x4 (1024 blocks), bf16
__global__ __launch_bounds__(256) void k_g1(const u16* __restrict__ Xb,
                                            const u16* __restrict__ Wb,
                                            float* __restrict__ Qacc) {
  __shared__ u16 As[128 * 64];
  __shared__ u16 Bs[64 * 64];
  int tid = threadIdx.x;
  int m0 = blockIdx.x * 128;
  int n0 = blockIdx.y * 64;
  int kt0 = blockIdx.z * 16;
  int w = tid >> 6, l = tid & 63;
  int l15 = l & 15, quad = l >> 4;
  int lr = l >> 3, lg = l & 7;
  f32x4 acc[2][4] = {};

  for (int kt = kt0; kt < kt0 + 16; ++kt) {
    #pragma unroll
    for (int i = 0; i < 4; ++i) {
      int wc = i * 4 + w;
      int row = wc * 8 + lr;
      int g = lg ^ (row & 7);
      GLDS(Xb + (size_t)(m0 + row) * KP + kt * 64 + g * 8, As + wc * 512);
      if (i < 2)
        GLDS(Wb + (size_t)(n0 + row) * KP + kt * 64 + g * 8, Bs + wc * 512);
    }
    __syncthreads();
    #pragma unroll
    for (int kk = 0; kk < 2; ++kk) {
      bf16x8 a[2], b[4];
      #pragma unroll
      for (int mi = 0; mi < 2; ++mi) {
        int arow = w * 32 + mi * 16 + l15;
        int slot = (kk * 4 + quad) ^ (arow & 7);
        a[mi] = *(const bf16x8*)&As[arow * 64 + slot * 8];
      }
      #pragma unroll
      for (int ni = 0; ni < 4; ++ni) {
        int brow = ni * 16 + l15;
        int slot = (kk * 4 + quad) ^ (brow & 7);
        b[ni] = *(const bf16x8*)&Bs[brow * 64 + slot * 8];
      }
      #pragma unroll
      for (int mi = 0; mi < 2; ++mi)
        #pragma unroll
        for (int ni = 0; ni < 4; ++ni)
          acc[mi][ni] = __builtin_amdgcn_mfma_f32_16x16x32_bf16(a[mi], b[ni], acc[mi][ni], 0, 0, 0);
    }
    __syncthreads();
  }
  float* dst = Qacc + (size_t)blockIdx.z * (MM * DD);
  #pragma unroll
  for (int mi = 0; mi < 2; ++mi)
    #pragma unroll
    for (int ni = 0; ni < 4; ++ni)
      #pragma unroll
      for (int r = 0; r < 4; ++r) {
        int m = m0 + w * 32 + mi * 16 + quad * 4 + r;
        int d = n0 + ni * 16 + l15;
        dst[(size_t)m * DD + d] = acc[mi][ni][r];
      }
}

// k_tanh4: q = tanh(sum of 4 partials); Qb bf16 + Qf fp8 (q*4, permuted)
__global__ __launch_bounds__(256) void k_tanh4(const float* __restrict__ Qacc,
                                               u16* __restrict__ Qb,
                                               u8* __restrict__ Qf) {
  int idx = blockIdx.x * 256 + threadIdx.x;
  size_t base = (size_t)idx * 8;
  f32x4 s0 = {0,0,0,0}, s1 = {0,0,0,0};
  #pragma unroll
  for (int z = 0; z < 4; ++z) {
    s0 += *(const f32x4*)(Qacc + (size_t)z * (MM * DD) + base);
    s1 += *(const f32x4*)(Qacc + (size_t)z * (MM * DD) + base + 4);
  }
  float t[8];
  #pragma unroll
  for (int j = 0; j < 4; ++j) t[j] = tanhf(s0[j]);
  #pragma unroll
  for (int j = 0; j < 4; ++j) t[4+j] = tanhf(s1[j]);
  u16x8 p;
  #pragma unroll
  for (int j = 0; j < 8; ++j) p[j] = f2bf(t[j]);
  *(u16x8*)(Qb + base) = p;
  u32x2 q8;
  q8[0] = pk4fp8(t[0] * 4.f, t[1] * 4.f, t[2] * 4.f, t[3] * 4.f);
  q8[1] = pk4fp8(t[4] * 4.f, t[5] * 4.f, t[6] * 4.f, t[7] * 4.f);
  int jg = (int)((base >> 3) & 7);
  size_t dest = (base & ~(size_t)63) + (size_t)pgrp(jg) * 8;
  *(u32x2*)(Qf + dest) = q8;
}

// k_s8: Pf = fp8(exp(q.E^T /64)/4). 128x128 tile, fp8 MFMA, b128 frag reads.
__global__ __launch_bounds__(256, 4) void k_s8(const u8* __restrict__ Qf,
                                               const u8* __restrict__ Ef,
                                               u8* __restrict__ Pf,
                                               float* __restrict__ Lacc) {
  __shared__ u8 S8[16384];       // As 8K | Bs 8K; epilogue: P-tile 16K
  u8* As = S8;
  u8* Bs = S8 + 8192;
  int tid = threadIdx.x;
  int m0 = blockIdx.x * 128;
  int n0 = blockIdx.y * 128;
  int w = tid >> 6, l = tid & 63;
  int l15 = l & 15, quad = l >> 4;
  int mhalf = w >> 1, nhalf = w & 1;
  int srow = tid >> 2, schunk = tid & 3;
  int sw = schunk ^ ((srow >> 1) & 3);          // same for row and row+64
  const u8* qa0 = Qf + (size_t)(m0 + srow) * DD + sw * 16;
  const u8* qa1 = Qf + (size_t)(m0 + 64 + srow) * DD + sw * 16;
  const u8* eb0 = Ef + (size_t)(n0 + srow) * DD + sw * 16;
  const u8* eb1 = Ef + (size_t)(n0 + 64 + srow) * DD + sw * 16;
  f32x4 acc[4][4] = {};

  for (int kt = 0; kt < 8; ++kt) {
    GLDS(qa0 + kt * 64, As + tid * 16);
    GLDS(qa1 + kt * 64, As + 4096 + tid * 16);
    GLDS(eb0 + kt * 64, Bs + tid * 16);
    GLDS(eb1 + kt * 64, Bs + 4096 + tid * 16);
    __syncthreads();
    longx2 a[4], b[4];
    #pragma unroll
    for (int mi = 0; mi < 4; ++mi)
      a[mi] = *(const longx2*)&As[fr16(mhalf * 64 + mi * 16 + l15, quad)];
    #pragma unroll
    for (int ni = 0; ni < 4; ++ni)
      b[ni] = *(const longx2*)&Bs[fr16(nhalf * 64 + ni * 16 + l15, quad)];
    #pragma unroll
    for (int mi = 0; mi < 4; ++mi)
      #pragma unroll
      for (int ni = 0; ni < 4; ++ni)
        acc[mi][ni] = __builtin_amdgcn_mfma_f32_16x16x32_fp8_fp8(a[mi][0], b[ni][0], acc[mi][ni], 0, 0, 0);
    #pragma unroll
    for (int mi = 0; mi < 4; ++mi)
      #pragma unroll
      for (int ni = 0; ni < 4; ++ni)
        acc[mi][ni] = __builtin_amdgcn_mfma_f32_16x16x32_fp8_fp8(a[mi][1], b[ni][1], acc[mi][ni], 0, 0, 0);
    __syncthreads();
  }

  // epilogue: pf = 2^(s*C2 - 2) = exp(s/64)/4; rowsum(pf) -> Lacc (l/4)
  const float C2 = 0.0225421100138901f;   // log2(e)/64
  float rs[4][4] = {};
  #pragma unroll
  for (int mi = 0; mi < 4; ++mi) {
    #pragma unroll
    for (int ni = 0; ni < 4; ++ni) {
      bool ok = (n0 + nhalf * 64 + ni * 16 + l15) < VV;
      // permuted in-tile byte col (frag-pair order for the PV consumer)
      int p_in = ((ni & 1) * 2 + (l15 >> 3)) * 16 + ((ni >> 1) << 3) + (l15 & 7);
      int gbyte = nhalf * 64 + p_in;
      int gch = gbyte >> 4, glo = gbyte & 15;
      float pf[4];
      #pragma unroll
      for (int r = 0; r < 4; ++r) {
        float t = fminf(fmaf(acc[mi][ni][r], C2, -2.f), 6.3f);
        float p = ok ? exp2f(t) : 0.f;
        pf[r] = p;
        rs[mi][r] += p;
      }
      u32 wpk = pk4fp8(pf[0], pf[1], pf[2], pf[3]);
      #pragma unroll
      for (int r = 0; r < 4; ++r) {
        int rowL = mhalf * 64 + mi * 16 + quad * 4 + r;
        S8[rowL * 128 + ((gch ^ (rowL & 7)) << 4) + glo] = (u8)(wpk >> (8 * r));
      }
    }
  }
  __syncthreads();
  { // coalesced Pf store: row = tid>>1, 64B half = tid&1
    int row = tid >> 1, h2 = tid & 1;
    size_t gbase = (size_t)(m0 + row) * VPAD + n0 + h2 * 64;
    #pragma unroll
    for (int c = 0; c < 4; ++c) {
      int slot = h2 * 4 + c;
      *(u32x4*)(Pf + gbase + c * 16) =
          *(const u32x4*)&S8[row * 128 + ((slot ^ (row & 7)) << 4)];
    }
  }
  #pragma unroll
  for (int mi = 0; mi < 4; ++mi)
    #pragma unroll
    for (int r = 0; r < 4; ++r) {
      float v = rs[mi][r];
      v += __shfl_xor(v, 1, 16);
      v += __shfl_xor(v, 2, 16);
      v += __shfl_xor(v, 4, 16);
      v += __shfl_xor(v, 8, 16);
      if (l15 == 0)
        atomicAdd(&Lacc[m0 + mhalf * 64 + mi * 16 + quad * 4 + r], v);
    }
}

// k_pvs8: Pacc[z] = Pf @ ETf, fp8, split-K x8 (1024 blocks, 20-iter loops)
__global__ __launch_bounds__(256, 4) void k_pvs8(const u8* __restrict__ Pf,
                                                 const u8* __restrict__ ETf,
                                                 float* __restrict__ Pacc) {
  __shared__ u8 S8[16384];
  u8* As = S8;
  u8* Bs = S8 + 8192;
  int tid = threadIdx.x;
  int m0 = blockIdx.x * 128;
  int d0 = blockIdx.y * 128;
  int z = blockIdx.z;
  int w = tid >> 6, l = tid & 63;
  int l15 = l & 15, quad = l >> 4;
  int mhalf = w >> 1, nhalf = w & 1;
  int srow = tid >> 2, schunk = tid & 3;
  int sw = schunk ^ ((srow >> 1) & 3);
  const u8* pa0 = Pf + (size_t)(m0 + srow) * VPAD + sw * 16;
  const u8* pa1 = Pf + (size_t)(m0 + 64 + srow) * VPAD + sw * 16;
  const u8* eb0 = ETf + (size_t)(d0 + srow) * VPAD + sw * 16;
  const u8* eb1 = ETf + (size_t)(d0 + 64 + srow) * VPAD + sw * 16;
  f32x4 acc[4][4] = {};
  int kt0 = z * 20;

  for (int kt = kt0; kt < kt0 + 20; ++kt) {
    GLDS(pa0 + kt * 64, As + tid * 16);
    GLDS(pa1 + kt * 64, As + 4096 + tid * 16);
    GLDS(eb0 + kt * 64, Bs + tid * 16);
    GLDS(eb1 + kt * 64, Bs + 4096 + tid * 16);
    __syncthreads();
    longx2 a[4], b[4];
    #pragma unroll
    for (int mi = 0; mi < 4; ++mi)
      a[mi] = *(const longx2*)&As[fr16(mhalf * 64 + mi * 16 + l15, quad)];
    #pragma unroll
    for (int ni = 0; ni < 4; ++ni)
      b[ni] = *(const longx2*)&Bs[fr16(nhalf * 64 + ni * 16 + l15, quad)];
    #pragma unroll
    for (int mi = 0; mi < 4; ++mi)
      #pragma unroll
      for (int ni = 0; ni < 4; ++ni)
        acc[mi][ni] = __builtin_amdgcn_mfma_f32_16x16x32_fp8_fp8(a[mi][0], b[ni][0], acc[mi][ni], 0, 0, 0);
    #pragma unroll
    for (int mi = 0; mi < 4; ++mi)
      #pragma unroll
      for (int ni = 0; ni < 4; ++ni)
        acc[mi][ni] = __builtin_amdgcn_mfma_f32_16x16x32_fp8_fp8(a[mi][1], b[ni][1], acc[mi][ni], 0, 0, 0);
    __syncthreads();
  }
  float* dst = Pacc + (size_t)z * (MM * DD);
  #pragma unroll
  for (int mi = 0; mi < 4; ++mi)
    #pragma unroll
    for (int ni = 0; ni < 4; ++ni)
      #pragma unroll
      for (int r = 0; r < 4; ++r) {
        int m = m0 + mhalf * 64 + mi * 16 + quad * 4 + r;
        int d = d0 + nhalf * 64 + ni * 16 + l15;
        dst[(size_t)m * DD + d] = acc[mi][ni][r];
      }
}

// k_fin8v2: out = (sum of 8 Pacc) / (16*Lacc) + q
__global__ __launch_bounds__(256) void k_fin8v2(float* __restrict__ Out,
                                                const float* __restrict__ Lacc,
                                                const u16* __restrict__ Qb,
                                                const float* __restrict__ Pacc) {
  int idx = blockIdx.x * 256 + threadIdx.x;
  int m = idx >> 7;
  int d4 = (idx & 127) * 4;
  float inv = 0.0625f / Lacc[m];
  size_t off = (size_t)m * DD + d4;
  f32x4 s = {0.f, 0.f, 0.f, 0.f};
  #pragma unroll
  for (int z = 0; z < 8; ++z)
    s += *(const f32x4*)(Pacc + (size_t)z * (MM * DD) + off);
  const u16* qp = Qb + off;
  f32x4 r;
  #pragma unroll
  for (int i = 0; i < 4; ++i) r[i] = s[i] * inv + bf2f(qp[i]);
  *(f32x4*)(Out + off) = r;
}

// =============================== bf16 fallback ===============================

__global__ __launch_bounds__(256) void k_eprep(const float* __restrict__ E,
                                               u16* __restrict__ Eb,
                                               u16* __restrict__ ETb,
                                               float* __restrict__ Out,
                                               float* __restrict__ Lacc) {
  __shared__ u16 st[64 * 65];
  int tid = threadIdx.x;
  {
    int bid = blockIdx.x * 8 + blockIdx.y;
    f32x4 z = {0.f, 0.f, 0.f, 0.f};
    #pragma unroll
    for (int rep = 0; rep < 2; ++rep) {
      int id = bid * 256 + tid + rep * 327680;
      if (id < 524288)      *(f32x4*)(Out + (size_t)id * 4) = z;
      else if (id < 525312) *(f32x4*)(Lacc + (size_t)(id - 524288) * 4) = z;
    }
  }
  int v0 = blockIdx.x * 64, d0 = blockIdx.y * 64;
  int r = tid >> 2, seg = tid & 3;
  u16 h[16];
  int v = v0 + r;
  if (v < VV) {
    const float* src = E + (size_t)v * DD + d0 + seg * 16;
    #pragma unroll
    for (int j = 0; j < 4; ++j) {
      float4 t = *(const float4*)(src + j * 4);
      h[4*j+0] = f2bf(t.x); h[4*j+1] = f2bf(t.y); h[4*j+2] = f2bf(t.z); h[4*j+3] = f2bf(t.w);
    }
  } else {
    #pragma unroll
    for (int j = 0; j < 16; ++j) h[j] = 0;
  }
  {
    u16x8 p0, p1;
    #pragma unroll
    for (int j = 0; j < 8; ++j) { p0[j] = h[j]; p1[j] = h[8+j]; }
    u16* dst = Eb + (size_t)v * DD + d0 + seg * 16;
    *(u16x8*)dst = p0; *(u16x8*)(dst + 8) = p1;
  }
  #pragma unroll
  for (int j = 0; j < 16; ++j) st[r * 65 + seg * 16 + j] = h[j];
  __syncthreads();
  {
    u16 g[16];
    #pragma unroll
    for (int j = 0; j < 16; ++j) g[j] = st[(seg * 16 + j) * 65 + r];
    u16x8 p0, p1;
    #pragma unroll
    for (int j = 0; j < 8; ++j) { p0[j] = g[j]; p1[j] = g[8+j]; }
    u16* dst = ETb + (size_t)(d0 + r) * VPAD + v0 + seg * 16;
    *(u16x8*)dst = p0; *(u16x8*)(dst + 8) = p1;
  }
}

__global__ __launch_bounds__(256) void k_gemm1(const float* __restrict__ X,
                                               const float* __restrict__ W,
                                               u16* __restrict__ Qb) {
  __shared__ u16 xs[64 * 64];
  __shared__ u16 wst[64 * 64];
  int tid = threadIdx.x;
  int m0 = blockIdx.x * 64;
  int n0 = blockIdx.y * 64;
  int srow = tid >> 2;
  int sseg = tid & 3;
  int r7 = srow & 7;
  const float* xsrc = X + (size_t)(m0 + srow) * CC + sseg * 16;
  const float* wsrc = W + (size_t)(n0 + srow) * CC + sseg * 16;
  int lane = tid & 63;
  int wv = tid >> 6;
  int l15 = lane & 15, quad = lane >> 4;
  f32x4 acc[4] = {};

  for (int kt = 0; kt < 63; ++kt) {
    int cbase = kt * 64 + sseg * 16;
    float xv[16], wf[16];
    if (cbase + 16 <= CC) {
      #pragma unroll
      for (int j = 0; j < 4; ++j) {
        float4 tx = *(const float4*)(xsrc + kt * 64 + j * 4);
        float4 tw = *(const float4*)(wsrc + kt * 64 + j * 4);
        xv[4*j+0] = tx.x; xv[4*j+1] = tx.y; xv[4*j+2] = tx.z; xv[4*j+3] = tx.w;
        wf[4*j+0] = tw.x; wf[4*j+1] = tw.y; wf[4*j+2] = tw.z; wf[4*j+3] = tw.w;
      }
    } else {
      #pragma unroll
      for (int j = 0; j < 16; ++j) { xv[j] = 0.f; wf[j] = 0.f; }
    }
    __syncthreads();
    #pragma unroll
    for (int j = 0; j < 2; ++j) {
      int g = (sseg * 2 + j) ^ r7;
      u16x8 px, pw;
      #pragma unroll
      for (int e = 0; e < 8; ++e) { px[e] = f2bf(xv[8*j+e]); pw[e] = f2bf(wf[8*j+e]); }
      *(u16x8*)&xs[srow * 64 + (g << 3)] = px;
      *(u16x8*)&wst[srow * 64 + (g << 3)] = pw;
    }
    __syncthreads();
    #pragma unroll
    for (int kk = 0; kk < 2; ++kk) {
      int arow = 16 * wv + l15;
      int ga = (kk * 4 + quad) ^ (arow & 7);
      bf16x8 a = *(const bf16x8*)&xs[arow * 64 + (ga << 3)];
      #pragma unroll
      for (int nb = 0; nb < 4; ++nb) {
        int brow = 16 * nb + l15;
        int gb = (kk * 4 + quad) ^ (brow & 7);
        bf16x8 b = *(const bf16x8*)&wst[brow * 64 + (gb << 3)];
        acc[nb] = __builtin_amdgcn_mfma_f32_16x16x32_bf16(a, b, acc[nb], 0, 0, 0);
      }
    }
  }
  #pragma unroll
  for (int nb = 0; nb < 4; ++nb) {
    int d = n0 + 16 * nb + l15;
    #pragma unroll
    for (int r = 0; r < 4; ++r) {
      int m = m0 + 16 * wv + 4 * quad + r;
      Qb[(size_t)m * DD + d] = f2bf(tanhf(acc[nb][r]));
    }
  }
}

__global__ __launch_bounds__(256) void k_s(const u16* __restrict__ Qb,
                                           const u16* __restrict__ Eb,
                                           u16* __restrict__ Pg,
                                           float* __restrict__ Lacc,
                                           int cbase, int W) {
  __shared__ u16 As[128 * 64];
  __shared__ u16 Bs[128 * 64];
  int tid = threadIdx.x;
  int m0 = blockIdx.x * 128;
  int n0 = blockIdx.y * 128;
  int w = tid >> 6, l = tid & 63;
  int l15 = l & 15, quad = l >> 4;
  int mhalf = w >> 1, nhalf = w & 1;
  int lr = l >> 3, lg = l & 7;
  f32x4 acc[4][4] = {};

  for (int kt = 0; kt < 8; ++kt) {
    #pragma unroll
    for (int i = 0; i < 4; ++i) {
      int wc = i * 4 + w;
      int row = wc * 8 + lr;
      int g = lg ^ (row & 7);
      GLDS(Qb + (size_t)(m0 + row) * DD + kt * 64 + g * 8, As + wc * 512);
      GLDS(Eb + (size_t)(cbase + n0 + row) * DD + kt * 64 + g * 8, Bs + wc * 512);
    }
    __syncthreads();
    #pragma unroll
    for (int kk = 0; kk < 2; ++kk) {
      bf16x8 a[4], b[4];
      #pragma unroll
      for (int mi = 0; mi < 4; ++mi) {
        int arow = mhalf * 64 + mi * 16 + l15;
        int slot = (kk * 4 + quad) ^ (arow & 7);
        a[mi] = *(const bf16x8*)&As[arow * 64 + slot * 8];
      }
      #pragma unroll
      for (int ni = 0; ni < 4; ++ni) {
        int brow = nhalf * 64 + ni * 16 + l15;
        int slot = (kk * 4 + quad) ^ (brow & 7);
        b[ni] = *(const bf16x8*)&Bs[brow * 64 + slot * 8];
      }
      #pragma unroll
      for (int mi = 0; mi < 4; ++mi)
        #pragma unroll
        for (int ni = 0; ni < 4; ++ni)
          acc[mi][ni] = __builtin_amdgcn_mfma_f32_16x16x32_bf16(a[mi], b[ni], acc[mi][ni], 0, 0, 0);
    }
    __syncthreads();
  }

  float rs[4][4] = {};
  #pragma unroll
  for (int mi = 0; mi < 4; ++mi) {
    #pragma unroll
    for (int ni = 0; ni < 4; ++ni) {
      int ncol = n0 + nhalf * 64 + ni * 16 + l15;
      bool ok = (cbase + ncol) < VV;
      #pragma unroll
      for (int r = 0; r < 4; ++r) {
        float p = ok ? __expf(acc[mi][ni][r]) : 0.f;
        rs[mi][r] += p;
        int m = m0 + mhalf * 64 + mi * 16 + quad * 4 + r;
        Pg[(size_t)m * W + ncol] = f2bf(p);
      }
    }
  }
  #pragma unroll
  for (int mi = 0; mi < 4; ++mi)
    #pragma unroll
    for (int r = 0; r < 4; ++r) {
      float v = rs[mi][r];
      v += __shfl_xor(v, 1, 16);
      v += __shfl_xor(v, 2, 16);
      v += __shfl_xor(v, 4, 16);
      v += __shfl_xor(v, 8, 16);
      if (l15 == 0)
        atomicAdd(&Lacc[m0 + mhalf * 64 + mi * 16 + quad * 4 + r], v);
    }
}

__global__ __launch_bounds__(256) void k_pv(const u16* __restrict__ Pg,
                                            const u16* __restrict__ ETb,
                                            float* __restrict__ Out,
                                            int cbase, int W) {
  __shared__ u16 As[128 * 64];
  __shared__ u16 Bs[64 * 64];
  int tid = threadIdx.x;
  int m0 = blockIdx.x * 128;
  int n0 = blockIdx.y * 64;
  int w = tid >> 6, l = tid & 63;
  int l15 = l & 15, quad = l >> 4;
  int lr = l >> 3, lg = l & 7;
  int iters = W >> 6;
  f32x4 acc[2][4] = {};

  for (int kt = 0; kt < iters; ++kt) {
    #pragma unroll
    for (int i = 0; i < 4; ++i) {
      int wc = i * 4 + w;
      int row = wc * 8 + lr;
      int g = lg ^ (row & 7);
      GLDS(Pg + (size_t)(m0 + row) * W + kt * 64 + g * 8, As + wc * 512);
      if (i < 2)
        GLDS(ETb + (size_t)(n0 + row) * VPAD + cbase + kt * 64 + g * 8, Bs + wc * 512);
    }
    __syncthreads();
    #pragma unroll
    for (int kk = 0; kk < 2; ++kk) {
      bf16x8 a[2], b[4];
      #pragma unroll
      for (int mi = 0; mi < 2; ++mi) {
        int arow = w * 32 + mi * 16 + l15;
        int slot = (kk * 4 + quad) ^ (arow & 7);
        a[mi] = *(const bf16x8*)&As[arow * 64 + slot * 8];
      }
      #pragma unroll
      for (int ni = 0; ni < 4; ++ni) {
        int brow = ni * 16 + l15;
        int slot = (kk * 4 + quad) ^ (brow & 7);
        b[ni] = *(const bf16x8*)&Bs[brow * 64 + slot * 8];
      }
      #pragma unroll
      for (int mi = 0; mi < 2; ++mi)
        #pragma unroll
        for (int ni = 0; ni < 4; ++ni)
          acc[mi][ni] = __builtin_amdgcn_mfma_f32_16x16x32_bf16(a[mi], b[ni], acc[mi][ni], 0, 0, 0);
    }
    __syncthreads();
  }
  #pragma unroll
  for (int mi = 0; mi < 2; ++mi)
    #pragma unroll
    for (int ni = 0; ni < 4; ++ni)
      #pragma unroll
      for (int r = 0; r < 4; ++r) {
        int m = m0 + w * 32 + mi * 16 + quad * 4 + r;
        int d = n0 + ni * 16 + l15;
        Out[(size_t)m * DD + d] += acc[mi][ni][r];
      }
}

__global__ __launch_bounds__(256) void k_fin(float* __restrict__ Out,
                                             const float* __restrict__ Lacc,
                                             const u16* __restrict__ Qb) {
  int idx = blockIdx.x * 256 + threadIdx.x;
  int m = idx >> 7;
  int d4 = (idx & 127) * 4;
  float inv = 1.f / Lacc[m];
  f32x4 ov = *(const f32x4*)(Out + (size_t)m * DD + d4);
  const u16* qp = Qb + (size_t)m * DD + d4;
  f32x4 r;
  #pragma unroll
  for (int i = 0; i < 4; ++i) r[i] = ov[i] * inv + bf2f(qp[i]);
  *(f32x4*)(Out + (size_t)m * DD + d4) = r;
}

extern "C" void kernel_launch(void* const* d_in, const int* in_sizes, int n_in,
                              void* d_out, int out_size, void* d_ws, size_t ws_size,
                              hipStream_t stream) {
  const float* x  = (const float*)d_in[0];
  const float* Wp = (const float*)d_in[1];
  const float* E  = (const float*)d_in[2];
  float* out = (float*)d_out;
  char* ws = (char*)d_ws;

  if (ws_size >= (size_t)FAST8_NEED) {
    u16*   Qb   = (u16*)(ws + WS8_QB);
    u8*    Qf   = (u8*)(ws + WS8_QF);
    u8*    Ef   = (u8*)(ws + WS8_EF);
    u8*    ETf  = (u8*)(ws + WS8_ETF);
    float* Lacc = (float*)(ws + WS8_LACC);
    u16*   Xb   = (u16*)(ws + WS8_R + R_XB);
    u16*   Wb   = (u16*)(ws + WS8_R + R_WB);
    float* Qacc = (float*)(ws + WS8_R + R_QA);
    u8*    Pf   = (u8*)(ws + WS8_R);
    float* Pacc = (float*)(ws + WS8_PACC);

    k_eprep8<<<dim3(VPAD / 64, DD / 64), 256, 0, stream>>>(E, Ef, ETf, Lacc);
    k_conv<<<dim3(MM + DD), 256, 0, stream>>>(x, Wp, Xb, Wb);
    k_g1<<<dim3(MM / 128, DD / 64, 4), 256, 0, stream>>>(Xb, Wb, Qacc);
    k_tanh4<<<dim3(MM * DD / 8 / 256), 256, 0, stream>>>(Qacc, Qb, Qf);
    k_s8<<<dim3(MM / 128, VPAD / 128), 256, 0, stream>>>(Qf, Ef, Pf, Lacc);
    k_pvs8<<<dim3(MM / 128, DD / 128, 8), 256, 0, stream>>>(Pf, ETf, Pacc);
    k_fin8v2<<<dim3(MM * DD / 4 / 256), 256, 0, stream>>>(out, Lacc, Qb, Pacc);
  } else {
    u16*   Qb   = (u16*)(ws + WS_Q);
    u16*   Eb   = (u16*)(ws + WS_EB);
    u16*   ETb  = (u16*)(ws + WS_ET);
    float* Lacc = (float*)(ws + WS_LACC);
    u16*   Pc   = (u16*)(ws + WS_P);
    int W = 640;
    if (ws_size >= (size_t)WS_P + (size_t)MM * 2560 * 2) W = 2560;
    else if (ws_size >= (size_t)WS_P + (size_t)MM * 1280 * 2) W = 1280;
    int nch = VPAD / W;
    k_eprep<<<dim3(VPAD / 64, DD / 64), 256, 0, stream>>>(E, Eb, ETb, out, Lacc);
    k_gemm1<<<dim3(MM / 64, DD / 64), 256, 0, stream>>>(x, Wp, Qb);
    for (int c = 0; c < nch; ++c) {
      k_s <<<dim3(MM / 128, W / 128), 256, 0, stream>>>(Qb, Eb, Pc, Lacc, c * W, W);
      k_pv<<<dim3(MM / 128, DD / 64), 256, 0, stream>>>(Pc, ETb, out, c * W, W);
    }
    k_fin<<<dim3(MM * DD / 4 / 256), 256, 0, stream>>>(out, Lacc, Qb);
  }
}